// Round 1
// baseline (229.825 us; speedup 1.0000x reference)
//
#include <hip/hip_runtime.h>
#include <math.h>

// ---- problem constants ----
constexpr int Bg   = 128;          // graphs
constexpr int Nn   = 128;          // nodes/graph
constexpr int E    = Bg * Nn * 8;  // 131072 edges
constexpr int IND  = 16;
constexpr int H    = 32;
constexpr int K1   = 64;
constexpr int K2   = 32;
constexpr int OUTD = 128;
constexpr int NC   = 2;
constexpr int N0   = Bg * Nn;      // 16384
constexpr int N1   = Bg * K1;      // 8192

// ---------------------------------------------------------------------------
// Phase-1 precompute: per-node matvecs for NNConv1, init h1 to bias,
// zero degree/agg buffers, relabel = -1.
__global__ void k_pre1(const float* __restrict__ h, const float* __restrict__ w2,
                       const float* __restrict__ b2, const float* __restrict__ conv_b,
                       float* __restrict__ hw2a, float* __restrict__ hba,
                       float* __restrict__ h1,
                       float* __restrict__ outdeg, float* __restrict__ indeg,
                       float* __restrict__ agg, int* __restrict__ relabel) {
    int idx = blockIdx.x * blockDim.x + threadIdx.x;
    if (idx < N0 * H) {
        int n = idx >> 5, o = idx & 31;
        const float* hn = h + n * IND;
        float sw = 0.f, sb = 0.f;
#pragma unroll
        for (int i = 0; i < IND; ++i) {
            float hv = hn[i];
            sw += hv * w2[i * H + o];
            sb += hv * b2[i * H + o];
        }
        hw2a[idx] = sw;
        hba[idx]  = sb;
        h1[idx]   = conv_b[o];
    }
    if (idx < N0) {
        outdeg[idx] = 0.f; indeg[idx] = 0.f; agg[idx] = 0.f; relabel[idx] = -1;
    }
}

// NNConv1 edge scatter: thread per (edge, out-dim). Also count degrees (lane 0).
__global__ void k_edge1(const float* __restrict__ e, const int* __restrict__ src,
                        const int* __restrict__ dst,
                        const float* __restrict__ w1, const float* __restrict__ b1,
                        const float* __restrict__ hw2a, const float* __restrict__ hba,
                        float* __restrict__ h1, float* __restrict__ outdeg,
                        float* __restrict__ indeg) {
    int idx = blockIdx.x * blockDim.x + threadIdx.x;
    if (idx >= E * H) return;
    int i = idx >> 5, o = idx & 31;
    int s = src[i], d = dst[i];
    float t = fmaxf(e[i] * w1[0] + b1[0], 0.f);
    atomicAdd(&h1[d * H + o], t * hw2a[s * H + o] + hba[s * H + o]);
    if (o == 0) {
        atomicAdd(&outdeg[s], 1.f);
        atomicAdd(&indeg[d], 1.f);
    }
}

// hw = hx @ W  (W is (H,1))
__global__ void k_nodedot(const float* __restrict__ hx, const float* __restrict__ wv,
                          float* __restrict__ hw, int n) {
    int idx = blockIdx.x * blockDim.x + threadIdx.x;
    if (idx >= n) return;
    const float* hn = hx + idx * H;
    float s = 0.f;
#pragma unroll
    for (int o = 0; o < H; ++o) s += hn[o] * wv[o];
    hw[idx] = s;
}

// GraphConv scatter, phase 1 (all edges valid).
__global__ void k_scatter1(const int* __restrict__ src, const int* __restrict__ dst,
                           const float* __restrict__ hw, const float* __restrict__ outdeg,
                           float* __restrict__ agg) {
    int i = blockIdx.x * blockDim.x + threadIdx.x;
    if (i >= E) return;
    int s = src[i], d = dst[i];
    atomicAdd(&agg[d], hw[s] * rsqrtf(fmaxf(outdeg[s], 1.f)));
}

// GraphConv scatter, phase 2 (relabelled, validity via relabel>=0).
__global__ void k_scatter2(const int* __restrict__ src, const int* __restrict__ dst,
                           const int* __restrict__ relabel,
                           const float* __restrict__ hw, const float* __restrict__ outdeg,
                           float* __restrict__ agg) {
    int i = blockIdx.x * blockDim.x + threadIdx.x;
    if (i >= E) return;
    int rs = relabel[src[i]], rd = relabel[dst[i]];
    if (rs < 0 || rd < 0) return;
    atomicAdd(&agg[rd], hw[rs] * rsqrtf(fmaxf(outdeg[rs], 1.f)));
}

// score = sigmoid(agg * indeg^-0.5 + b)
__global__ void k_score(const float* __restrict__ agg, const float* __restrict__ indeg,
                        const float* __restrict__ bptr, float* __restrict__ out, int n) {
    int i = blockIdx.x * blockDim.x + threadIdx.x;
    if (i >= n) return;
    float v = agg[i] * rsqrtf(fmaxf(indeg[i], 1.f)) + bptr[0];
    out[i] = 1.f / (1.f + expf(-v));
}

// Stable top-k (descending, ties -> lower index) via rank computation.
// One block per graph, NPER threads. Gathers gated kept features; optionally
// fills relabel with new global ids.
template <int NPER, int KK>
__global__ void k_topk(const float* __restrict__ score, const float* __restrict__ hsrc,
                       float* __restrict__ hkept, int* __restrict__ relabel) {
    __shared__ float ss[NPER];
    __shared__ int   wloc[KK];
    __shared__ float wsc[KK];
    int b = blockIdx.x, t = threadIdx.x;
    ss[t] = score[b * NPER + t];
    __syncthreads();
    float my = ss[t];
    int rank = 0;
    for (int j = 0; j < NPER; ++j) {
        float sj = ss[j];
        rank += (sj > my) || (sj == my && j < t);
    }
    if (rank < KK) {
        if (relabel) relabel[b * NPER + t] = b * KK + rank;
        wloc[rank] = t;
        wsc[rank]  = my;
    }
    __syncthreads();
    for (int w = t; w < KK * H; w += NPER) {
        int jj = w >> 5, o = w & 31;
        int g = b * NPER + wloc[jj];
        hkept[(b * KK + jj) * H + o] = hsrc[g * H + o] * wsc[jj];
    }
}

// readout: mean || max over KK nodes, per feature dim. One block/graph, H threads.
template <int KK>
__global__ void k_readout(const float* __restrict__ hk, float* __restrict__ g) {
    int b = blockIdx.x, o = threadIdx.x;
    float s = 0.f, m = -INFINITY;
    for (int j = 0; j < KK; ++j) {
        float v = hk[(b * KK + j) * H + o];
        s += v;
        m = fmaxf(m, v);
    }
    g[b * 2 * H + o]     = s * (1.f / KK);
    g[b * 2 * H + H + o] = m;
}

// Phase-2 precompute (din = H).
__global__ void k_pre2(const float* __restrict__ h1p, const float* __restrict__ w2,
                       const float* __restrict__ b2, const float* __restrict__ conv_b,
                       float* __restrict__ hw2b, float* __restrict__ hbb,
                       float* __restrict__ h2,
                       float* __restrict__ outdeg, float* __restrict__ indeg,
                       float* __restrict__ agg) {
    int idx = blockIdx.x * blockDim.x + threadIdx.x;
    if (idx < N1 * H) {
        int n = idx >> 5, o = idx & 31;
        const float* hn = h1p + n * H;
        float sw = 0.f, sb = 0.f;
#pragma unroll
        for (int i = 0; i < H; ++i) {
            float hv = hn[i];
            sw += hv * w2[i * H + o];
            sb += hv * b2[i * H + o];
        }
        hw2b[idx] = sw;
        hbb[idx]  = sb;
        h2[idx]   = conv_b[o];
    }
    if (idx < N1) { outdeg[idx] = 0.f; indeg[idx] = 0.f; agg[idx] = 0.f; }
}

// NNConv2 edge scatter with relabel/validity.
__global__ void k_edge2(const float* __restrict__ e, const int* __restrict__ src,
                        const int* __restrict__ dst, const int* __restrict__ relabel,
                        const float* __restrict__ w1, const float* __restrict__ b1,
                        const float* __restrict__ hw2b, const float* __restrict__ hbb,
                        float* __restrict__ h2, float* __restrict__ outdeg,
                        float* __restrict__ indeg) {
    int idx = blockIdx.x * blockDim.x + threadIdx.x;
    if (idx >= E * H) return;
    int i = idx >> 5, o = idx & 31;
    int rs = relabel[src[i]], rd = relabel[dst[i]];
    if (rs < 0 || rd < 0) return;
    float t = fmaxf(e[i] * w1[0] + b1[0], 0.f);
    atomicAdd(&h2[rd * H + o], t * hw2b[rs * H + o] + hbb[rs * H + o]);
    if (o == 0) {
        atomicAdd(&outdeg[rs], 1.f);
        atomicAdd(&indeg[rd], 1.f);
    }
}

// Final MLP head: one block per graph, 128 threads.
__global__ void k_mlp(const float* __restrict__ g1, const float* __restrict__ g2,
                      const float* __restrict__ fc1_w, const float* __restrict__ fc1_b,
                      const float* __restrict__ bn4_g, const float* __restrict__ bn4_b,
                      const float* __restrict__ fc2_w, const float* __restrict__ fc2_b,
                      const float* __restrict__ bn5_g, const float* __restrict__ bn5_b,
                      const float* __restrict__ fc3_w, const float* __restrict__ fc3_b,
                      float* __restrict__ out) {
    __shared__ float x[OUTD], y1[OUTD], y2[H], z[NC];
    int b = blockIdx.x, t = threadIdx.x;
    x[t] = (t < 2 * H) ? g1[b * 2 * H + t] : g2[b * 2 * H + (t - 2 * H)];
    __syncthreads();
    const float inv = rsqrtf(1.f + 1e-5f);
    float a = fc1_b[t];
    for (int k = 0; k < OUTD; ++k) a += x[k] * fc1_w[k * OUTD + t];
    y1[t] = fmaxf(a, 0.f) * inv * bn4_g[t] + bn4_b[t];
    __syncthreads();
    if (t < H) {
        float a2 = fc2_b[t];
        for (int k = 0; k < OUTD; ++k) a2 += y1[k] * fc2_w[k * H + t];
        y2[t] = fmaxf(a2, 0.f) * inv * bn5_g[t] + bn5_b[t];
    }
    __syncthreads();
    if (t < NC) {
        float a3 = fc3_b[t];
        for (int k = 0; k < H; ++k) a3 += y2[k] * fc3_w[k * NC + t];
        z[t] = a3;
    }
    __syncthreads();
    if (t < NC) {
        float m = fmaxf(z[0], z[1]);
        float l = m + logf(expf(z[0] - m) + expf(z[1] - m));
        out[b * NC + t] = z[t] - l;
    }
}

// ---------------------------------------------------------------------------
extern "C" void kernel_launch(void* const* d_in, const int* in_sizes, int n_in,
                              void* d_out, int out_size, void* d_ws, size_t ws_size,
                              hipStream_t stream) {
    // inputs (setup_inputs dict order)
    const float* h       = (const float*)d_in[0];
    const float* e       = (const float*)d_in[1];
    const int*   src     = (const int*)d_in[2];
    const int*   dst     = (const int*)d_in[3];
    const float* n1_w1   = (const float*)d_in[4];
    const float* n1_b1   = (const float*)d_in[5];
    const float* n1_w2   = (const float*)d_in[6];
    const float* n1_b2   = (const float*)d_in[7];
    const float* conv1_b = (const float*)d_in[8];
    const float* p1_w    = (const float*)d_in[9];
    const float* p1_b    = (const float*)d_in[10];
    const float* n2_w1   = (const float*)d_in[11];
    const float* n2_b1   = (const float*)d_in[12];
    const float* n2_w2   = (const float*)d_in[13];
    const float* n2_b2   = (const float*)d_in[14];
    const float* conv2_b = (const float*)d_in[15];
    const float* p2_w    = (const float*)d_in[16];
    const float* p2_b    = (const float*)d_in[17];
    const float* fc1_w   = (const float*)d_in[18];
    const float* fc1_b   = (const float*)d_in[19];
    const float* bn4_g   = (const float*)d_in[20];
    const float* bn4_b   = (const float*)d_in[21];
    const float* fc2_w   = (const float*)d_in[22];
    const float* fc2_b   = (const float*)d_in[23];
    const float* bn5_g   = (const float*)d_in[24];
    const float* bn5_b   = (const float*)d_in[25];
    const float* fc3_w   = (const float*)d_in[26];
    const float* fc3_b   = (const float*)d_in[27];

    // outputs: x (B*NC) | score1 (N0) | score2 (N1)
    float* out_x  = (float*)d_out;
    float* out_s1 = out_x + Bg * NC;
    float* out_s2 = out_s1 + N0;

    // workspace arena (floats)
    float* w = (float*)d_ws;
    float* h1      = w; w += N0 * H;
    float* hw2a    = w; w += N0 * H;
    float* hba     = w; w += N0 * H;
    float* outdeg0 = w; w += N0;
    float* indeg0  = w; w += N0;
    float* hw1n    = w; w += N0;
    float* agg1    = w; w += N0;
    float* h1p     = w; w += N1 * H;
    float* g1      = w; w += Bg * 2 * H;
    float* hw2b    = w; w += N1 * H;
    float* hbb     = w; w += N1 * H;
    float* h2      = w; w += N1 * H;
    float* outdeg1 = w; w += N1;
    float* indeg1  = w; w += N1;
    float* hw2n    = w; w += N1;
    float* agg2    = w; w += N1;
    float* h2p     = w; w += Bg * K2 * H;
    float* g2      = w; w += Bg * 2 * H;
    int*   relabel = (int*)w;

    const int TB = 256;
    // phase 1
    k_pre1<<<(N0 * H + TB - 1) / TB, TB, 0, stream>>>(h, n1_w2, n1_b2, conv1_b,
                                                      hw2a, hba, h1, outdeg0, indeg0,
                                                      agg1, relabel);
    k_edge1<<<(E * H + TB - 1) / TB, TB, 0, stream>>>(e, src, dst, n1_w1, n1_b1,
                                                      hw2a, hba, h1, outdeg0, indeg0);
    k_nodedot<<<(N0 + TB - 1) / TB, TB, 0, stream>>>(h1, p1_w, hw1n, N0);
    k_scatter1<<<(E + TB - 1) / TB, TB, 0, stream>>>(src, dst, hw1n, outdeg0, agg1);
    k_score<<<(N0 + TB - 1) / TB, TB, 0, stream>>>(agg1, indeg0, p1_b, out_s1, N0);
    k_topk<Nn, K1><<<Bg, Nn, 0, stream>>>(out_s1, h1, h1p, relabel);
    k_readout<K1><<<Bg, H, 0, stream>>>(h1p, g1);
    // phase 2
    k_pre2<<<(N1 * H + TB - 1) / TB, TB, 0, stream>>>(h1p, n2_w2, n2_b2, conv2_b,
                                                      hw2b, hbb, h2, outdeg1, indeg1,
                                                      agg2);
    k_edge2<<<(E * H + TB - 1) / TB, TB, 0, stream>>>(e, src, dst, relabel, n2_w1,
                                                      n2_b1, hw2b, hbb, h2, outdeg1,
                                                      indeg1);
    k_nodedot<<<(N1 + TB - 1) / TB, TB, 0, stream>>>(h2, p2_w, hw2n, N1);
    k_scatter2<<<(E + TB - 1) / TB, TB, 0, stream>>>(src, dst, relabel, hw2n, outdeg1,
                                                     agg2);
    k_score<<<(N1 + TB - 1) / TB, TB, 0, stream>>>(agg2, indeg1, p2_b, out_s2, N1);
    k_topk<K1, K2><<<Bg, K1, 0, stream>>>(out_s2, h2, h2p, nullptr);
    k_readout<K2><<<Bg, H, 0, stream>>>(h2p, g2);
    // head
    k_mlp<<<Bg, OUTD, 0, stream>>>(g1, g2, fc1_w, fc1_b, bn4_g, bn4_b,
                                   fc2_w, fc2_b, bn5_g, bn5_b, fc3_w, fc3_b, out_x);
}

// Round 2
// 200.461 us; speedup vs baseline: 1.1465x; 1.1465x over previous
//
#include <hip/hip_runtime.h>
#include <math.h>

// ---- problem constants ----
constexpr int Bg   = 128;          // graphs
constexpr int Nn   = 128;          // nodes/graph
constexpr int Epg  = Nn * 8;       // 1024 edges/graph
constexpr int IND  = 16;
constexpr int H    = 32;
constexpr int K1   = 64;
constexpr int K2   = 32;
constexpr int OUTD = 128;
constexpr int NC   = 2;

// One block per graph; the whole forward lives in LDS.
__launch_bounds__(256)
__global__ void k_fused(const float* __restrict__ h, const float* __restrict__ e,
                        const int* __restrict__ src, const int* __restrict__ dst,
                        const float* __restrict__ n1_w1, const float* __restrict__ n1_b1,
                        const float* __restrict__ n1_w2, const float* __restrict__ n1_b2,
                        const float* __restrict__ conv1_b,
                        const float* __restrict__ p1_w, const float* __restrict__ p1_b,
                        const float* __restrict__ n2_w1, const float* __restrict__ n2_b1,
                        const float* __restrict__ n2_w2, const float* __restrict__ n2_b2,
                        const float* __restrict__ conv2_b,
                        const float* __restrict__ p2_w, const float* __restrict__ p2_b,
                        const float* __restrict__ fc1_w, const float* __restrict__ fc1_b,
                        const float* __restrict__ bn4_g, const float* __restrict__ bn4_b,
                        const float* __restrict__ fc2_w, const float* __restrict__ fc2_b,
                        const float* __restrict__ bn5_g, const float* __restrict__ bn5_b,
                        const float* __restrict__ fc3_w, const float* __restrict__ fc3_b,
                        float* __restrict__ out_x, float* __restrict__ out_s1,
                        float* __restrict__ out_s2) {
    // arenas (phase-1 name | phase-2 reuse)
    __shared__ float sA[4096];   // hw2a          | h1p(0:2048), h2(2048:4096)
    __shared__ float sB[4096];   // hba           | hw2b(0:2048), hbb(2048:4096)
    __shared__ float sC[4096];   // h-in(0:2048)->h1 | h2p(0:1024)
    __shared__ float sT[Epg];    // raw e -> (pass2) t2
    __shared__ int   sSD[Epg];   // packed local src | dst<<8
    __shared__ int   sDegO[Nn], sDegI[Nn];
    __shared__ float sAgg[Nn], sHwn[Nn], sScore[Nn];
    __shared__ int   sRel[Nn];
    __shared__ int   sWloc[K1];
    __shared__ float sWsc[K1];
    __shared__ float sG1[2 * H], sG2[2 * H];
    __shared__ float sX[OUTD], sY1[OUTD], sY2[H], sZ[NC];

    const int b = blockIdx.x, t = threadIdx.x;

    // ---- stage inputs ----
    for (int i = t; i < Nn * IND; i += 256) sC[i] = h[b * Nn * IND + i];
    for (int i = t; i < Epg; i += 256) {
        sT[i] = e[b * Epg + i];
        int s = src[b * Epg + i] & (Nn - 1);
        int d = dst[b * Epg + i] & (Nn - 1);
        sSD[i] = s | (d << 8);
    }
    if (t < Nn) { sDegO[t] = 0; sDegI[t] = 0; sAgg[t] = 0.f; }
    __syncthreads();

    // ---- NNConv1 per-node matvecs: hw2a = h@w2, hba = h@b2 ----
    for (int i = t; i < Nn * H; i += 256) {
        int n = i >> 5, o = i & 31;
        const float* hn = &sC[n * IND];
        float sw = 0.f, sb = 0.f;
#pragma unroll
        for (int k = 0; k < IND; ++k) {
            float hv = hn[k];
            sw += hv * n1_w2[k * H + o];
            sb += hv * n1_b2[k * H + o];
        }
        sA[i] = sw; sB[i] = sb;
    }
    __syncthreads();
    // ---- h1 = conv1_b (overwrites h staging) ----
    for (int i = t; i < Nn * H; i += 256) sC[i] = conv1_b[i & 31];
    __syncthreads();

    // ---- NNConv1 edge scatter (LDS atomics) + degrees ----
    {
        const float w1a = n1_w1[0], b1a = n1_b1[0];
        const int o = t & 31;
        for (int i = t >> 5; i < Epg; i += 8) {
            int sd = sSD[i]; int s = sd & 255, d = sd >> 8;
            float tv = fmaxf(sT[i] * w1a + b1a, 0.f);
            atomicAdd(&sC[d * H + o], tv * sA[s * H + o] + sB[s * H + o]);
        }
        for (int i = t; i < Epg; i += 256) {
            int sd = sSD[i];
            atomicAdd(&sDegO[sd & 255], 1);
            atomicAdd(&sDegI[sd >> 8], 1);
        }
    }
    __syncthreads();

    // ---- SAGPool1 score: GraphConv(h1) -> sigmoid ----
    if (t < Nn) {
        const float* hn = &sC[t * H];
        float s0 = 0.f;
#pragma unroll
        for (int o = 0; o < H; ++o) s0 += hn[o] * p1_w[o];
        sHwn[t] = s0;
    }
    __syncthreads();
    for (int i = t; i < Epg; i += 256) {
        int sd = sSD[i]; int s = sd & 255, d = sd >> 8;
        atomicAdd(&sAgg[d], sHwn[s] * rsqrtf(fmaxf((float)sDegO[s], 1.f)));
    }
    __syncthreads();
    if (t < Nn) {
        float v = sAgg[t] * rsqrtf(fmaxf((float)sDegI[t], 1.f)) + p1_b[0];
        float sc = 1.f / (1.f + expf(-v));
        sScore[t] = sc;
        out_s1[b * Nn + t] = sc;
    }
    __syncthreads();

    // ---- top-k1 (stable descending rank) ----
    if (t < Nn) {
        float my = sScore[t];
        int rank = 0;
        for (int j = 0; j < Nn; ++j) {
            float sj = sScore[j];
            rank += (sj > my) || (sj == my && j < t);
        }
        sRel[t] = -1;
        if (rank < K1) { sRel[t] = rank; sWloc[rank] = t; sWsc[rank] = my; }
    }
    __syncthreads();
    // gather gated h1p -> sA[0:2048]
    for (int i = t; i < K1 * H; i += 256) {
        int j = i >> 5, o = i & 31;
        sA[i] = sC[sWloc[j] * H + o] * sWsc[j];
    }
    __syncthreads();
    // readout g1 (mean || max)
    if (t < H) {
        float s = 0.f, m = -INFINITY;
        for (int j = 0; j < K1; ++j) { float v = sA[j * H + t]; s += v; m = fmaxf(m, v); }
        sG1[t] = s * (1.f / K1); sG1[H + t] = m;
    }
    __syncthreads();

    // ---- phase 2 precompute: hw2b/hbb from h1p; t2; init h2; reset degs ----
    for (int i = t; i < K1 * H; i += 256) {
        int n = i >> 5, o = i & 31;
        const float* hn = &sA[n * H];
        float sw = 0.f, sb = 0.f;
#pragma unroll
        for (int k = 0; k < H; ++k) {
            float hv = hn[k];
            sw += hv * n2_w2[k * H + o];
            sb += hv * n2_b2[k * H + o];
        }
        sB[i] = sw; sB[2048 + i] = sb;
    }
    {
        const float w1b = n2_w1[0], b1b = n2_b1[0];
        for (int i = t; i < Epg; i += 256) sT[i] = fmaxf(sT[i] * w1b + b1b, 0.f);
    }
    for (int i = t; i < K1 * H; i += 256) sA[2048 + i] = conv2_b[i & 31];
    if (t < K1) { sDegO[t] = 0; sDegI[t] = 0; sAgg[t] = 0.f; }
    __syncthreads();

    // ---- NNConv2 edge scatter (valid = both kept) ----
    {
        const int o = t & 31;
        for (int i = t >> 5; i < Epg; i += 8) {
            int sd = sSD[i]; int rs = sRel[sd & 255], rd = sRel[sd >> 8];
            if (rs >= 0 && rd >= 0)
                atomicAdd(&sA[2048 + rd * H + o], sT[i] * sB[rs * H + o] + sB[2048 + rs * H + o]);
        }
        for (int i = t; i < Epg; i += 256) {
            int sd = sSD[i]; int rs = sRel[sd & 255], rd = sRel[sd >> 8];
            if (rs >= 0 && rd >= 0) { atomicAdd(&sDegO[rs], 1); atomicAdd(&sDegI[rd], 1); }
        }
    }
    __syncthreads();

    // ---- SAGPool2 score ----
    if (t < K1) {
        const float* hn = &sA[2048 + t * H];
        float s0 = 0.f;
#pragma unroll
        for (int o = 0; o < H; ++o) s0 += hn[o] * p2_w[o];
        sHwn[t] = s0;
    }
    __syncthreads();
    for (int i = t; i < Epg; i += 256) {
        int sd = sSD[i]; int rs = sRel[sd & 255], rd = sRel[sd >> 8];
        if (rs >= 0 && rd >= 0)
            atomicAdd(&sAgg[rd], sHwn[rs] * rsqrtf(fmaxf((float)sDegO[rs], 1.f)));
    }
    __syncthreads();
    if (t < K1) {
        float v = sAgg[t] * rsqrtf(fmaxf((float)sDegI[t], 1.f)) + p2_b[0];
        float sc = 1.f / (1.f + expf(-v));
        sScore[t] = sc;
        out_s2[b * K1 + t] = sc;
    }
    __syncthreads();

    // ---- top-k2 ----
    if (t < K1) {
        float my = sScore[t];
        int rank = 0;
        for (int j = 0; j < K1; ++j) {
            float sj = sScore[j];
            rank += (sj > my) || (sj == my && j < t);
        }
        if (rank < K2) { sWloc[rank] = t; sWsc[rank] = my; }
    }
    __syncthreads();
    for (int i = t; i < K2 * H; i += 256) {
        int j = i >> 5, o = i & 31;
        sC[i] = sA[2048 + sWloc[j] * H + o] * sWsc[j];
    }
    __syncthreads();
    if (t < H) {
        float s = 0.f, m = -INFINITY;
        for (int j = 0; j < K2; ++j) { float v = sC[j * H + t]; s += v; m = fmaxf(m, v); }
        sG2[t] = s * (1.f / K2); sG2[H + t] = m;
    }
    __syncthreads();

    // ---- MLP head ----
    if (t < OUTD) sX[t] = (t < 2 * H) ? sG1[t] : sG2[t - 2 * H];
    __syncthreads();
    const float inv = rsqrtf(1.f + 1e-5f);
    if (t < OUTD) {
        float a = fc1_b[t];
        for (int k = 0; k < OUTD; ++k) a += sX[k] * fc1_w[k * OUTD + t];
        sY1[t] = fmaxf(a, 0.f) * inv * bn4_g[t] + bn4_b[t];
    }
    __syncthreads();
    if (t < H) {
        float a = fc2_b[t];
        for (int k = 0; k < OUTD; ++k) a += sY1[k] * fc2_w[k * H + t];
        sY2[t] = fmaxf(a, 0.f) * inv * bn5_g[t] + bn5_b[t];
    }
    __syncthreads();
    if (t < NC) {
        float a = fc3_b[t];
        for (int k = 0; k < H; ++k) a += sY2[k] * fc3_w[k * NC + t];
        sZ[t] = a;
    }
    __syncthreads();
    if (t < NC) {
        float m = fmaxf(sZ[0], sZ[1]);
        float l = m + logf(expf(sZ[0] - m) + expf(sZ[1] - m));
        out_x[b * NC + t] = sZ[t] - l;
    }
}

// ---------------------------------------------------------------------------
extern "C" void kernel_launch(void* const* d_in, const int* in_sizes, int n_in,
                              void* d_out, int out_size, void* d_ws, size_t ws_size,
                              hipStream_t stream) {
    const float* h       = (const float*)d_in[0];
    const float* e       = (const float*)d_in[1];
    const int*   src     = (const int*)d_in[2];
    const int*   dst     = (const int*)d_in[3];
    const float* n1_w1   = (const float*)d_in[4];
    const float* n1_b1   = (const float*)d_in[5];
    const float* n1_w2   = (const float*)d_in[6];
    const float* n1_b2   = (const float*)d_in[7];
    const float* conv1_b = (const float*)d_in[8];
    const float* p1_w    = (const float*)d_in[9];
    const float* p1_b    = (const float*)d_in[10];
    const float* n2_w1   = (const float*)d_in[11];
    const float* n2_b1   = (const float*)d_in[12];
    const float* n2_w2   = (const float*)d_in[13];
    const float* n2_b2   = (const float*)d_in[14];
    const float* conv2_b = (const float*)d_in[15];
    const float* p2_w    = (const float*)d_in[16];
    const float* p2_b    = (const float*)d_in[17];
    const float* fc1_w   = (const float*)d_in[18];
    const float* fc1_b   = (const float*)d_in[19];
    const float* bn4_g   = (const float*)d_in[20];
    const float* bn4_b   = (const float*)d_in[21];
    const float* fc2_w   = (const float*)d_in[22];
    const float* fc2_b   = (const float*)d_in[23];
    const float* bn5_g   = (const float*)d_in[24];
    const float* bn5_b   = (const float*)d_in[25];
    const float* fc3_w   = (const float*)d_in[26];
    const float* fc3_b   = (const float*)d_in[27];

    float* out_x  = (float*)d_out;
    float* out_s1 = out_x + Bg * NC;
    float* out_s2 = out_s1 + Bg * Nn;

    k_fused<<<Bg, 256, 0, stream>>>(h, e, src, dst,
                                    n1_w1, n1_b1, n1_w2, n1_b2, conv1_b, p1_w, p1_b,
                                    n2_w1, n2_b1, n2_w2, n2_b2, conv2_b, p2_w, p2_b,
                                    fc1_w, fc1_b, bn4_g, bn4_b, fc2_w, fc2_b,
                                    bn5_g, bn5_b, fc3_w, fc3_b,
                                    out_x, out_s1, out_s2);
}

// Round 3
// 187.764 us; speedup vs baseline: 1.2240x; 1.0676x over previous
//
#include <hip/hip_runtime.h>
#include <math.h>

// ---- problem constants ----
constexpr int Bg   = 128;          // graphs
constexpr int Nn   = 128;          // nodes/graph
constexpr int Epg  = Nn * 8;       // 1024 edges/graph
constexpr int IND  = 16;
constexpr int H    = 32;
constexpr int K1   = 64;
constexpr int K2   = 32;
constexpr int OUTD = 128;
constexpr int NC   = 2;
constexpr int BS   = 1024;         // threads per block (16 waves)

// One block per graph; the whole forward lives in LDS.
__launch_bounds__(BS)
__global__ void k_fused(const float* __restrict__ h, const float* __restrict__ e,
                        const int* __restrict__ src, const int* __restrict__ dst,
                        const float* __restrict__ n1_w1, const float* __restrict__ n1_b1,
                        const float* __restrict__ n1_w2, const float* __restrict__ n1_b2,
                        const float* __restrict__ conv1_b,
                        const float* __restrict__ p1_w, const float* __restrict__ p1_b,
                        const float* __restrict__ n2_w1, const float* __restrict__ n2_b1,
                        const float* __restrict__ n2_w2, const float* __restrict__ n2_b2,
                        const float* __restrict__ conv2_b,
                        const float* __restrict__ p2_w, const float* __restrict__ p2_b,
                        const float* __restrict__ fc1_w, const float* __restrict__ fc1_b,
                        const float* __restrict__ bn4_g, const float* __restrict__ bn4_b,
                        const float* __restrict__ fc2_w, const float* __restrict__ fc2_b,
                        const float* __restrict__ bn5_g, const float* __restrict__ bn5_b,
                        const float* __restrict__ fc3_w, const float* __restrict__ fc3_b,
                        float* __restrict__ out_x, float* __restrict__ out_s1,
                        float* __restrict__ out_s2) {
    // arenas (phase-1 name | later reuse)
    __shared__ float sA[4096];   // hw2a          | h1p(0:2048), h2(2048:4096)
    __shared__ float sB[4096];   // hba           | hw2b(0:2048), hbb(2048:4096) | MLP partials
    __shared__ float sC[4096];   // h-in(0:2048) -> h1 | h2p(0:1024)
    __shared__ float sT[Epg];    // raw e -> (pass2) t2
    __shared__ int   sSD[Epg];   // packed local src | dst<<8
    __shared__ int   sDegO[Nn], sDegI[Nn];
    __shared__ float sAgg[Nn], sHwn[Nn], sScore[Nn];
    __shared__ int   sRel[Nn];
    __shared__ int   sWloc[K1];
    __shared__ float sWsc[K1];
    __shared__ float sG1[2 * H], sG2[2 * H];
    __shared__ float sY1[OUTD], sY2[H], sZ[NC];

    const int b = blockIdx.x, t = threadIdx.x;

    // ---- stage inputs ----
    for (int i = t; i < Nn * IND; i += BS) sC[i] = h[b * Nn * IND + i];
    if (t < Epg) {
        sT[t] = e[b * Epg + t];
        int s = src[b * Epg + t] & (Nn - 1);
        int d = dst[b * Epg + t] & (Nn - 1);
        sSD[t] = s | (d << 8);
    }
    if (t < Nn) { sDegO[t] = 0; sDegI[t] = 0; sAgg[t] = 0.f; }
    __syncthreads();

    // ---- NNConv1 per-node matvecs: hw2a = h@w2, hba = h@b2 ----
#pragma unroll
    for (int i = t; i < Nn * H; i += BS) {
        int n = i >> 5, o = i & 31;
        const float* hn = &sC[n * IND];
        float sw = 0.f, sb = 0.f;
#pragma unroll
        for (int k = 0; k < IND; ++k) {
            float hv = hn[k];
            sw += hv * n1_w2[k * H + o];
            sb += hv * n1_b2[k * H + o];
        }
        sA[i] = sw; sB[i] = sb;
    }
    __syncthreads();
    // ---- h1 = conv1_b (overwrites h staging) + degree counting ----
#pragma unroll
    for (int i = t; i < Nn * H; i += BS) sC[i] = conv1_b[i & 31];
    if (t < Epg) {
        int sd = sSD[t];
        atomicAdd(&sDegO[sd & 255], 1);
        atomicAdd(&sDegI[sd >> 8], 1);
    }
    __syncthreads();

    // ---- NNConv1 edge scatter (LDS atomics) ----
    {
        const float w1a = n1_w1[0], b1a = n1_b1[0];
        const int o = t & 31;
#pragma unroll 4
        for (int i = t >> 5; i < Epg; i += BS / 32) {
            int sd = sSD[i]; int s = sd & 255, d = sd >> 8;
            float tv = fmaxf(sT[i] * w1a + b1a, 0.f);
            atomicAdd(&sC[d * H + o], tv * sA[s * H + o] + sB[s * H + o]);
        }
    }
    __syncthreads();

    // ---- SAGPool1 score: GraphConv(h1) -> sigmoid ----
    if (t < Nn) {
        const float* hn = &sC[t * H];
        float s0 = 0.f;
#pragma unroll
        for (int o = 0; o < H; ++o) s0 += hn[o] * p1_w[o];
        sHwn[t] = s0;
    }
    __syncthreads();
    if (t < Epg) {
        int sd = sSD[t]; int s = sd & 255, d = sd >> 8;
        atomicAdd(&sAgg[d], sHwn[s] * rsqrtf(fmaxf((float)sDegO[s], 1.f)));
    }
    __syncthreads();
    if (t < Nn) {
        float v = sAgg[t] * rsqrtf(fmaxf((float)sDegI[t], 1.f)) + p1_b[0];
        float sc = 1.f / (1.f + expf(-v));
        sScore[t] = sc;
        out_s1[b * Nn + t] = sc;
    }
    __syncthreads();

    // ---- top-k1 (stable descending rank) ----
    if (t < Nn) {
        float my = sScore[t];
        int rank = 0;
#pragma unroll 8
        for (int j = 0; j < Nn; ++j) {
            float sj = sScore[j];
            rank += (sj > my) || (sj == my && j < t);
        }
        sRel[t] = -1;
        if (rank < K1) { sRel[t] = rank; sWloc[rank] = t; sWsc[rank] = my; }
    }
    __syncthreads();
    // gather gated h1p -> sA[0:2048]
#pragma unroll
    for (int i = t; i < K1 * H; i += BS) {
        int j = i >> 5, o = i & 31;
        sA[i] = sC[sWloc[j] * H + o] * sWsc[j];
    }
    __syncthreads();
    // readout g1 (mean || max): t<32 sums, t in [32,64) maxes
    if (t < 2 * H) {
        int o = t & 31;
        if (t < H) {
            float s = 0.f;
#pragma unroll 8
            for (int j = 0; j < K1; ++j) s += sA[j * H + o];
            sG1[o] = s * (1.f / K1);
        } else {
            float m = -INFINITY;
#pragma unroll 8
            for (int j = 0; j < K1; ++j) m = fmaxf(m, sA[j * H + o]);
            sG1[H + o] = m;
        }
    }
    // ---- phase 2 precompute: hw2b/hbb from h1p; t2; init h2; reset degs ----
    // (independent of readout; no barrier needed before these writes except sB)
    __syncthreads();
#pragma unroll
    for (int i = t; i < K1 * H; i += BS) {
        int n = i >> 5, o = i & 31;
        const float* hn = &sA[n * H];
        float sw = 0.f, sb = 0.f;
#pragma unroll
        for (int k = 0; k < H; ++k) {
            float hv = hn[k];
            sw += hv * n2_w2[k * H + o];
            sb += hv * n2_b2[k * H + o];
        }
        sB[i] = sw; sB[2048 + i] = sb;
    }
    {
        const float w1b = n2_w1[0], b1b = n2_b1[0];
        if (t < Epg) sT[t] = fmaxf(sT[t] * w1b + b1b, 0.f);
    }
#pragma unroll
    for (int i = t; i < K1 * H; i += BS) sA[2048 + i] = conv2_b[i & 31];
    if (t < K1) { sDegO[t] = 0; sDegI[t] = 0; sAgg[t] = 0.f; }
    __syncthreads();

    // ---- NNConv2 degree count ----
    if (t < Epg) {
        int sd = sSD[t]; int rs = sRel[sd & 255], rd = sRel[sd >> 8];
        if (rs >= 0 && rd >= 0) { atomicAdd(&sDegO[rs], 1); atomicAdd(&sDegI[rd], 1); }
    }
    // ---- NNConv2 edge scatter (valid = both kept) ----
    {
        const int o = t & 31;
#pragma unroll 4
        for (int i = t >> 5; i < Epg; i += BS / 32) {
            int sd = sSD[i]; int rs = sRel[sd & 255], rd = sRel[sd >> 8];
            if (rs >= 0 && rd >= 0)
                atomicAdd(&sA[2048 + rd * H + o],
                          sT[i] * sB[rs * H + o] + sB[2048 + rs * H + o]);
        }
    }
    __syncthreads();

    // ---- SAGPool2 score ----
    if (t < K1) {
        const float* hn = &sA[2048 + t * H];
        float s0 = 0.f;
#pragma unroll
        for (int o = 0; o < H; ++o) s0 += hn[o] * p2_w[o];
        sHwn[t] = s0;
    }
    __syncthreads();
    if (t < Epg) {
        int sd = sSD[t]; int rs = sRel[sd & 255], rd = sRel[sd >> 8];
        if (rs >= 0 && rd >= 0)
            atomicAdd(&sAgg[rd], sHwn[rs] * rsqrtf(fmaxf((float)sDegO[rs], 1.f)));
    }
    __syncthreads();
    if (t < K1) {
        float v = sAgg[t] * rsqrtf(fmaxf((float)sDegI[t], 1.f)) + p2_b[0];
        float sc = 1.f / (1.f + expf(-v));
        sScore[t] = sc;
        out_s2[b * K1 + t] = sc;
    }
    __syncthreads();

    // ---- top-k2 ----
    if (t < K1) {
        float my = sScore[t];
        int rank = 0;
#pragma unroll 8
        for (int j = 0; j < K1; ++j) {
            float sj = sScore[j];
            rank += (sj > my) || (sj == my && j < t);
        }
        if (rank < K2) { sWloc[rank] = t; sWsc[rank] = my; }
    }
    __syncthreads();
    if (t < K2 * H) {
        int j = t >> 5, o = t & 31;
        sC[t] = sA[2048 + sWloc[j] * H + o] * sWsc[j];
    }
    __syncthreads();
    if (t < 2 * H) {
        int o = t & 31;
        if (t < H) {
            float s = 0.f;
#pragma unroll 8
            for (int j = 0; j < K2; ++j) s += sC[j * H + o];
            sG2[o] = s * (1.f / K2);
        } else {
            float m = -INFINITY;
#pragma unroll 8
            for (int j = 0; j < K2; ++j) m = fmaxf(m, sC[j * H + o]);
            sG2[H + o] = m;
        }
    }
    __syncthreads();

    // ---- MLP head ----
    const float inv = rsqrtf(1.f + 1e-5f);
    // fc1: 128 outs x 128 k, split-k 8 ways -> sB[0:1024] partials
    {
        int o = t & 127, p = t >> 7;         // p in [0,8)
        float a = 0.f;
#pragma unroll
        for (int k = p * 16; k < p * 16 + 16; ++k) {
            float xv = (k < 2 * H) ? sG1[k] : sG2[k - 2 * H];
            a += xv * fc1_w[k * OUTD + o];
        }
        sB[p * OUTD + o] = a;
    }
    __syncthreads();
    if (t < OUTD) {
        float a = fc1_b[t];
#pragma unroll
        for (int p = 0; p < 8; ++p) a += sB[p * OUTD + t];
        sY1[t] = fmaxf(a, 0.f) * inv * bn4_g[t] + bn4_b[t];
    }
    __syncthreads();
    // fc2: 32 outs x 128 k, split-k 32 ways -> sB[1024:2048]
    {
        int o = t & 31, p = t >> 5;          // p in [0,32)
        float a = 0.f;
#pragma unroll
        for (int k = p * 4; k < p * 4 + 4; ++k) a += sY1[k] * fc2_w[k * H + o];
        sB[1024 + p * H + o] = a;
    }
    __syncthreads();
    if (t < H) {
        float a = fc2_b[t];
#pragma unroll
        for (int p = 0; p < 32; ++p) a += sB[1024 + p * H + t];
        sY2[t] = fmaxf(a, 0.f) * inv * bn5_g[t] + bn5_b[t];
    }
    __syncthreads();
    if (t < NC) {
        float a = fc3_b[t];
#pragma unroll
        for (int k = 0; k < H; ++k) a += sY2[k] * fc3_w[k * NC + t];
        sZ[t] = a;
    }
    __syncthreads();
    if (t < NC) {
        float m = fmaxf(sZ[0], sZ[1]);
        float l = m + logf(expf(sZ[0] - m) + expf(sZ[1] - m));
        out_x[b * NC + t] = sZ[t] - l;
    }
}

// ---------------------------------------------------------------------------
extern "C" void kernel_launch(void* const* d_in, const int* in_sizes, int n_in,
                              void* d_out, int out_size, void* d_ws, size_t ws_size,
                              hipStream_t stream) {
    const float* h       = (const float*)d_in[0];
    const float* e       = (const float*)d_in[1];
    const int*   src     = (const int*)d_in[2];
    const int*   dst     = (const int*)d_in[3];
    const float* n1_w1   = (const float*)d_in[4];
    const float* n1_b1   = (const float*)d_in[5];
    const float* n1_w2   = (const float*)d_in[6];
    const float* n1_b2   = (const float*)d_in[7];
    const float* conv1_b = (const float*)d_in[8];
    const float* p1_w    = (const float*)d_in[9];
    const float* p1_b    = (const float*)d_in[10];
    const float* n2_w1   = (const float*)d_in[11];
    const float* n2_b1   = (const float*)d_in[12];
    const float* n2_w2   = (const float*)d_in[13];
    const float* n2_b2   = (const float*)d_in[14];
    const float* conv2_b = (const float*)d_in[15];
    const float* p2_w    = (const float*)d_in[16];
    const float* p2_b    = (const float*)d_in[17];
    const float* fc1_w   = (const float*)d_in[18];
    const float* fc1_b   = (const float*)d_in[19];
    const float* bn4_g   = (const float*)d_in[20];
    const float* bn4_b   = (const float*)d_in[21];
    const float* fc2_w   = (const float*)d_in[22];
    const float* fc2_b   = (const float*)d_in[23];
    const float* bn5_g   = (const float*)d_in[24];
    const float* bn5_b   = (const float*)d_in[25];
    const float* fc3_w   = (const float*)d_in[26];
    const float* fc3_b   = (const float*)d_in[27];

    float* out_x  = (float*)d_out;
    float* out_s1 = out_x + Bg * NC;
    float* out_s2 = out_s1 + Bg * Nn;

    k_fused<<<Bg, BS, 0, stream>>>(h, e, src, dst,
                                   n1_w1, n1_b1, n1_w2, n1_b2, conv1_b, p1_w, p1_b,
                                   n2_w1, n2_b1, n2_w2, n2_b2, conv2_b, p2_w, p2_b,
                                   fc1_w, fc1_b, bn4_g, bn4_b, fc2_w, fc2_b,
                                   bn5_g, bn5_b, fc3_w, fc3_b,
                                   out_x, out_s1, out_s2);
}

// Round 4
// 159.059 us; speedup vs baseline: 1.4449x; 1.1805x over previous
//
#include <hip/hip_runtime.h>
#include <math.h>

// ---- problem constants ----
constexpr int Bg   = 128;          // graphs
constexpr int Nn   = 128;          // nodes/graph
constexpr int Epg  = Nn * 8;       // 1024 edges/graph
constexpr int IND  = 16;
constexpr int H    = 32;
constexpr int K1   = 64;
constexpr int K2   = 32;
constexpr int OUTD = 128;
constexpr int NC   = 2;
constexpr int BS   = 1024;         // 16 waves

// One block per graph. CSR-gather formulation: no feature atomics, 16 barriers.
__launch_bounds__(BS)
__global__ void k_fused(const float* __restrict__ h, const float* __restrict__ e,
                        const int* __restrict__ src, const int* __restrict__ dst,
                        const float* __restrict__ n1_w1, const float* __restrict__ n1_b1,
                        const float* __restrict__ n1_w2, const float* __restrict__ n1_b2,
                        const float* __restrict__ conv1_b,
                        const float* __restrict__ p1_w, const float* __restrict__ p1_b,
                        const float* __restrict__ n2_w1, const float* __restrict__ n2_b1,
                        const float* __restrict__ n2_w2, const float* __restrict__ n2_b2,
                        const float* __restrict__ conv2_b,
                        const float* __restrict__ p2_w, const float* __restrict__ p2_b,
                        const float* __restrict__ fc1_w, const float* __restrict__ fc1_b,
                        const float* __restrict__ bn4_g, const float* __restrict__ bn4_b,
                        const float* __restrict__ fc2_w, const float* __restrict__ fc2_b,
                        const float* __restrict__ bn5_g, const float* __restrict__ bn5_b,
                        const float* __restrict__ fc3_w, const float* __restrict__ fc3_b,
                        float* __restrict__ out_x, float* __restrict__ out_s1,
                        float* __restrict__ out_s2) {
    __shared__ float sA[4096];            // hw2a | h1p(0:2048)
    __shared__ float sB[4096];            // hba  | hw2b(0:2048)+hbb(2048:4096) | fc1 partials
    __shared__ float sC[4096];            // h-in(0:2048) -> h1 -> h2(0:2048)
    __shared__ float sT[Epg];             // raw edge scalar
    __shared__ unsigned short sSD[Epg];   // local src | dst<<8
    __shared__ unsigned short sCsr[Epg];  // edge ids sorted by dst
    __shared__ int   sDegO[Nn], sDegI[Nn], sRow[Nn], sCur[Nn]; // sCur reused: deg2O(0:64)|deg2I(64:128)
    __shared__ float sHwn[Nn], sScore[Nn];
    __shared__ int   sRel[Nn], sWloc[K1];
    __shared__ float sWsc[K1], sG1[2 * H], sG2[2 * H], sY1[OUTD];

    const int b = blockIdx.x, t = threadIdx.x;
    const int o5 = t & 31;

    // hoisted scalars / per-lane columns
    const float w1a = n1_w1[0], b1a = n1_b1[0];
    const float w1b = n2_w1[0], b1b = n2_b1[0];
    const float p1b = p1_b[0],  p2b = p2_b[0];
    const float p1wv = p1_w[o5], p2wv = p2_w[o5];
    const float c1b = conv1_b[o5], c2b = conv2_b[o5];
    const float inv = rsqrtf(1.f + 1e-5f);

    // ---- P0: stage inputs, zero degree counters ----
    sC[t]        = h[b * Nn * IND + t];
    sC[t + 1024] = h[b * Nn * IND + t + 1024];
    {
        sT[t] = e[b * Epg + t];
        int s = src[b * Epg + t] & (Nn - 1);
        int d = dst[b * Epg + t] & (Nn - 1);
        sSD[t] = (unsigned short)(s | (d << 8));
    }
    if (t < Nn) { sDegO[t] = 0; sDegI[t] = 0; }
    __syncthreads();

    // ---- P1: degree count (1 edge/thread) || NNConv1 matvec (hw2a, hba) ----
    {
        int sd = sSD[t];
        atomicAdd(&sDegO[sd & 255], 1);
        atomicAdd(&sDegI[sd >> 8], 1);
    }
    {
        float w2c[IND], b2c[IND];
#pragma unroll
        for (int k = 0; k < IND; ++k) {
            w2c[k] = n1_w2[k * H + o5];
            b2c[k] = n1_b2[k * H + o5];
        }
#pragma unroll
        for (int j = 0; j < 4; ++j) {
            int n = (t >> 5) + j * 32;
            const float* hn = &sC[n * IND];
            float sw = 0.f, sb = 0.f;
#pragma unroll
            for (int k = 0; k < IND; ++k) { float hv = hn[k]; sw += hv * w2c[k]; sb += hv * b2c[k]; }
            sA[n * H + o5] = sw;
            sB[n * H + o5] = sb;
        }
    }
    __syncthreads();

    // ---- P2: exclusive prefix scan of indeg (wave 0, 2 nodes/lane) ----
    if (t < 64) {
        int d0 = sDegI[2 * t], d1 = sDegI[2 * t + 1];
        int v = d0 + d1;
#pragma unroll
        for (int off = 1; off < 64; off <<= 1) {
            int u = __shfl_up(v, off);
            if (t >= off) v += u;
        }
        int excl = v - d0 - d1;
        sRow[2 * t] = excl;         sRow[2 * t + 1] = excl + d0;
        sCur[2 * t] = excl;         sCur[2 * t + 1] = excl + d0;
    }
    __syncthreads();

    // ---- P3: CSR placement (counting sort by dst) ----
    {
        int d = sSD[t] >> 8;
        int pos = atomicAdd(&sCur[d], 1);
        sCsr[pos] = (unsigned short)t;
    }
    __syncthreads();

    // ---- P4: NNConv1 gather -> h1 (sC), fused hwn1 shfl-reduce ----
#pragma unroll
    for (int j = 0; j < 4; ++j) {
        int n = (t >> 5) + j * 32;
        int row = sRow[n], cnt = sDegI[n];
        float acc = c1b;
        for (int jj = 0; jj < cnt; ++jj) {
            int ed = sCsr[row + jj];
            int s  = sSD[ed] & 255;
            float tv = fmaxf(sT[ed] * w1a + b1a, 0.f);
            acc += tv * sA[s * H + o5] + sB[s * H + o5];
        }
        sC[n * H + o5] = acc;
        float v = acc * p1wv;
#pragma unroll
        for (int m = 16; m >= 1; m >>= 1) v += __shfl_xor(v, m);
        if (o5 == 0) sHwn[n] = v;
    }
    __syncthreads();

    // ---- P5: GraphConv agg1 gather + sigmoid -> score1 ----
    if (t < Nn) {
        int row = sRow[t], cnt = sDegI[t];
        float acc = 0.f;
        for (int jj = 0; jj < cnt; ++jj) {
            int ed = sCsr[row + jj];
            int s  = sSD[ed] & 255;
            acc += sHwn[s] * rsqrtf(fmaxf((float)sDegO[s], 1.f));
        }
        float v = acc * rsqrtf(fmaxf((float)sDegI[t], 1.f)) + p1b;
        float sc = 1.f / (1.f + expf(-v));
        sScore[t] = sc;
        out_s1[b * Nn + t] = sc;
    }
    __syncthreads();

    // ---- P6: top-k1 (stable rank) ; threads 128..255 zero cursor area for deg2 ----
    if (t < Nn) {
        float my = sScore[t];
        int rank = 0;
#pragma unroll 4
        for (int j = 0; j < Nn; ++j) {
            float sj = sScore[j];
            rank += (sj > my) || (sj == my && j < t);
        }
        sRel[t] = (rank < K1) ? rank : -1;
        if (rank < K1) { sWloc[rank] = t; sWsc[rank] = my; }
    } else if (t < 2 * Nn) {
        sCur[t - Nn] = 0;
    }
    __syncthreads();

    // ---- P7: gather gated h1p -> sA[0:2048] ; count phase-2 degrees into sCur ----
    {
        int r0 = t >> 5;
        sA[t]        = sC[sWloc[r0] * H + o5] * sWsc[r0];
        int r1 = (t + 1024) >> 5;
        sA[t + 1024] = sC[sWloc[r1] * H + o5] * sWsc[r1];
    }
    {
        int sd = sSD[t];
        int rs = sRel[sd & 255], rd = sRel[sd >> 8];
        if (rs >= 0 && rd >= 0) {
            atomicAdd(&sCur[rs], 1);          // outdeg2
            atomicAdd(&sCur[64 + rd], 1);     // indeg2
        }
    }
    __syncthreads();

    // ---- P8: NNConv2 matvec (hw2b,hbb from h1p) || readout g1 ----
#pragma unroll
    for (int j = 0; j < 2; ++j) {
        int i = t + j * 1024;
        int n = i >> 5;
        const float* hn = &sA[n * H];
        float sw = 0.f, sb = 0.f;
#pragma unroll
        for (int k = 0; k < H; ++k) {
            float hv = hn[k];
            sw += hv * n2_w2[k * H + o5];
            sb += hv * n2_b2[k * H + o5];
        }
        sB[i] = sw; sB[2048 + i] = sb;
    }
    if (t < 2 * H) {
        if (t < H) {
            float s = 0.f;
#pragma unroll 8
            for (int j = 0; j < K1; ++j) s += sA[j * H + o5];
            sG1[o5] = s * (1.f / K1);
        } else {
            float m = -INFINITY;
#pragma unroll 8
            for (int j = 0; j < K1; ++j) m = fmaxf(m, sA[j * H + o5]);
            sG1[H + o5] = m;
        }
    }
    __syncthreads();

    // ---- P9: NNConv2 gather -> h2 (sC[0:2048]), fused hwn2 ----
#pragma unroll
    for (int j = 0; j < 2; ++j) {
        int i = t + j * 1024;
        int r = i >> 5;                       // kept index 0..63
        int n = sWloc[r];
        int row = sRow[n], cnt = sDegI[n];
        float acc = c2b;
        for (int jj = 0; jj < cnt; ++jj) {
            int ed = sCsr[row + jj];
            int rs = sRel[sSD[ed] & 255];
            if (rs >= 0) {
                float tv = fmaxf(sT[ed] * w1b + b1b, 0.f);
                acc += tv * sB[rs * H + o5] + sB[2048 + rs * H + o5];
            }
        }
        sC[r * H + o5] = acc;
        float v = acc * p2wv;
#pragma unroll
        for (int m = 16; m >= 1; m >>= 1) v += __shfl_xor(v, m);
        if (o5 == 0) sHwn[r] = v;
    }
    __syncthreads();

    // ---- P10: agg2 gather + sigmoid -> score2 ----
    if (t < K1) {
        int n = sWloc[t];
        int row = sRow[n], cnt = sDegI[n];
        float acc = 0.f;
        for (int jj = 0; jj < cnt; ++jj) {
            int ed = sCsr[row + jj];
            int rs = sRel[sSD[ed] & 255];
            if (rs >= 0) acc += sHwn[rs] * rsqrtf(fmaxf((float)sCur[rs], 1.f));
        }
        float v = acc * rsqrtf(fmaxf((float)sCur[64 + t], 1.f)) + p2b;
        float sc = 1.f / (1.f + expf(-v));
        sScore[t] = sc;
        out_s2[b * K1 + t] = sc;
    }
    __syncthreads();

    // ---- P11: top-k2 ----
    if (t < K1) {
        float my = sScore[t];
        int rank = 0;
#pragma unroll 4
        for (int j = 0; j < K1; ++j) {
            float sj = sScore[j];
            rank += (sj > my) || (sj == my && j < t);
        }
        if (rank < K2) { sWloc[rank] = t; sWsc[rank] = my; }
    }
    __syncthreads();

    // ---- P12: fused gather + readout g2 ----
    if (t < 2 * H) {
        if (t < H) {
            float s = 0.f;
#pragma unroll 8
            for (int j = 0; j < K2; ++j) s += sC[sWloc[j] * H + o5] * sWsc[j];
            sG2[o5] = s * (1.f / K2);
        } else {
            float m = -INFINITY;
#pragma unroll 8
            for (int j = 0; j < K2; ++j) m = fmaxf(m, sC[sWloc[j] * H + o5] * sWsc[j]);
            sG2[H + o5] = m;
        }
    }
    __syncthreads();

    // ---- P13: fc1 split-k partials (8-way) ----
    {
        int o = t & 127, p = t >> 7;
        float a = 0.f;
#pragma unroll
        for (int k = p * 16; k < p * 16 + 16; ++k) {
            float xv = (k < 2 * H) ? sG1[k] : sG2[k - 2 * H];
            a += xv * fc1_w[k * OUTD + o];
        }
        sB[p * OUTD + o] = a;
    }
    __syncthreads();

    // ---- P14: fc1 reduce + BN+ReLU ----
    if (t < OUTD) {
        float a = fc1_b[t];
#pragma unroll
        for (int p = 0; p < 8; ++p) a += sB[p * OUTD + t];
        sY1[t] = fmaxf(a, 0.f) * inv * bn4_g[t] + bn4_b[t];
    }
    __syncthreads();

    // ---- P15: tail on wave 0: fc2 + BN + fc3 + log_softmax ----
    if (t < 64) {
        int half = t >> 5;
        float a = 0.f;
#pragma unroll 8
        for (int k = 0; k < 64; ++k) {
            int kk = half * 64 + k;
            a += sY1[kk] * fc2_w[kk * H + o5];
        }
        a += __shfl_xor(a, 32);
        float y2 = fmaxf(a + fc2_b[o5], 0.f) * inv * bn5_g[o5] + bn5_b[o5];
        float v0 = (t < 32) ? y2 * fc3_w[o5 * NC + 0] : 0.f;
        float v1 = (t < 32) ? y2 * fc3_w[o5 * NC + 1] : 0.f;
#pragma unroll
        for (int m = 32; m >= 1; m >>= 1) {
            v0 += __shfl_xor(v0, m);
            v1 += __shfl_xor(v1, m);
        }
        if (t == 0) {
            float z0 = v0 + fc3_b[0], z1 = v1 + fc3_b[1];
            float mm = fmaxf(z0, z1);
            float l = mm + logf(expf(z0 - mm) + expf(z1 - mm));
            out_x[b * NC + 0] = z0 - l;
            out_x[b * NC + 1] = z1 - l;
        }
    }
}

// ---------------------------------------------------------------------------
extern "C" void kernel_launch(void* const* d_in, const int* in_sizes, int n_in,
                              void* d_out, int out_size, void* d_ws, size_t ws_size,
                              hipStream_t stream) {
    const float* h       = (const float*)d_in[0];
    const float* e       = (const float*)d_in[1];
    const int*   src     = (const int*)d_in[2];
    const int*   dst     = (const int*)d_in[3];
    const float* n1_w1   = (const float*)d_in[4];
    const float* n1_b1   = (const float*)d_in[5];
    const float* n1_w2   = (const float*)d_in[6];
    const float* n1_b2   = (const float*)d_in[7];
    const float* conv1_b = (const float*)d_in[8];
    const float* p1_w    = (const float*)d_in[9];
    const float* p1_b    = (const float*)d_in[10];
    const float* n2_w1   = (const float*)d_in[11];
    const float* n2_b1   = (const float*)d_in[12];
    const float* n2_w2   = (const float*)d_in[13];
    const float* n2_b2   = (const float*)d_in[14];
    const float* conv2_b = (const float*)d_in[15];
    const float* p2_w    = (const float*)d_in[16];
    const float* p2_b    = (const float*)d_in[17];
    const float* fc1_w   = (const float*)d_in[18];
    const float* fc1_b   = (const float*)d_in[19];
    const float* bn4_g   = (const float*)d_in[20];
    const float* bn4_b   = (const float*)d_in[21];
    const float* fc2_w   = (const float*)d_in[22];
    const float* fc2_b   = (const float*)d_in[23];
    const float* bn5_g   = (const float*)d_in[24];
    const float* bn5_b   = (const float*)d_in[25];
    const float* fc3_w   = (const float*)d_in[26];
    const float* fc3_b   = (const float*)d_in[27];

    float* out_x  = (float*)d_out;
    float* out_s1 = out_x + Bg * NC;
    float* out_s2 = out_s1 + Bg * Nn;

    k_fused<<<Bg, BS, 0, stream>>>(h, e, src, dst,
                                   n1_w1, n1_b1, n1_w2, n1_b2, conv1_b, p1_w, p1_b,
                                   n2_w1, n2_b1, n2_w2, n2_b2, conv2_b, p2_w, p2_b,
                                   fc1_w, fc1_b, bn4_g, bn4_b, fc2_w, fc2_b,
                                   bn5_g, bn5_b, fc3_w, fc3_b,
                                   out_x, out_s1, out_s2);
}

// Round 5
// 135.895 us; speedup vs baseline: 1.6912x; 1.1705x over previous
//
#include <hip/hip_runtime.h>
#include <math.h>

// ---- problem constants ----
constexpr int Bg   = 128;          // graphs
constexpr int Nn   = 128;          // nodes/graph
constexpr int Epg  = Nn * 8;       // 1024 edges/graph
constexpr int IND  = 16;
constexpr int H    = 32;
constexpr int K1   = 64;
constexpr int K2   = 32;
constexpr int OUTD = 128;
constexpr int NC   = 2;
constexpr int BS   = 1024;         // 16 waves

// One block per graph. Payload-CSR gather, fixed-trip unrolled inner loops.
__launch_bounds__(BS)
__global__ void k_fused(const float* __restrict__ h, const float* __restrict__ e,
                        const int* __restrict__ src, const int* __restrict__ dst,
                        const float* __restrict__ n1_w1, const float* __restrict__ n1_b1,
                        const float* __restrict__ n1_w2, const float* __restrict__ n1_b2,
                        const float* __restrict__ conv1_b,
                        const float* __restrict__ p1_w, const float* __restrict__ p1_b,
                        const float* __restrict__ n2_w1, const float* __restrict__ n2_b1,
                        const float* __restrict__ n2_w2, const float* __restrict__ n2_b2,
                        const float* __restrict__ conv2_b,
                        const float* __restrict__ p2_w, const float* __restrict__ p2_b,
                        const float* __restrict__ fc1_w, const float* __restrict__ fc1_b,
                        const float* __restrict__ bn4_g, const float* __restrict__ bn4_b,
                        const float* __restrict__ fc2_w, const float* __restrict__ fc2_b,
                        const float* __restrict__ bn5_g, const float* __restrict__ bn5_b,
                        const float* __restrict__ fc3_w, const float* __restrict__ fc3_b,
                        float* __restrict__ out_x, float* __restrict__ out_s1,
                        float* __restrict__ out_s2) {
    __shared__ float sA[4096];        // hw2a | h1p
    __shared__ float sB[4096];        // hba  | hw2b(0:2048)+hbb(2048:4096) | fc1 partials
    __shared__ float sC[4096];        // h-in(0:2048) -> h1 -> h2(0:2048)
    __shared__ uint2 sP[Epg + 8];     // CSR payload: (e_bits, src), padded
    __shared__ int   sDegO[Nn], sDegI[Nn], sRow[Nn], sCur[Nn];
    __shared__ float sHwnN[Nn], sScore[Nn];  // sScore doubles as agg accumulator
    __shared__ int   sRel[Nn], sWloc[K1];
    __shared__ float sWsc[K1], sG1[2 * H], sG2[2 * H], sY1[OUTD];

    const int b = blockIdx.x, t = threadIdx.x;
    const int o5 = t & 31;

    // ---- P0: issue all staging loads (independent), stage, zero counters ----
    const float ev = e[b * Epg + t];
    const int   es = src[b * Epg + t] & (Nn - 1);
    const int   ed = dst[b * Epg + t] & (Nn - 1);
    const float2 h2v = ((const float2*)h)[b * (Nn * IND / 2) + t];
    float w2c[IND], b2c[IND];
#pragma unroll
    for (int k = 0; k < IND; ++k) {
        w2c[k] = n1_w2[k * H + o5];
        b2c[k] = n1_b2[k * H + o5];
    }
    const float w1a = n1_w1[0], b1a = n1_b1[0];
    const float w1b = n2_w1[0], b1b = n2_b1[0];
    const float p1b = p1_b[0],  p2b = p2_b[0];
    const float p1wv = p1_w[o5], p2wv = p2_w[o5];
    const float c1b = conv1_b[o5], c2b = conv2_b[o5];
    const float inv = rsqrtf(1.f + 1e-5f);

    ((float2*)sC)[t] = h2v;
    if (t < Nn) { sDegO[t] = 0; sDegI[t] = 0; }
    __syncthreads();                                   // B0

    // ---- P1: degree count (regs) || NNConv1 matvec ----
    atomicAdd(&sDegO[es], 1);
    atomicAdd(&sDegI[ed], 1);
#pragma unroll
    for (int j = 0; j < 4; ++j) {
        int n = (t >> 5) + j * 32;
        const float* hn = &sC[n * IND];
        float sw = 0.f, sb = 0.f;
#pragma unroll
        for (int k = 0; k < IND; ++k) { float hv = hn[k]; sw += hv * w2c[k]; sb += hv * b2c[k]; }
        sA[n * H + o5] = sw;
        sB[n * H + o5] = sb;
    }
    __syncthreads();                                   // B1

    // ---- P2: prefix scan of indeg (wave 0) || zero agg1 ----
    if (t < 64) {
        int d0 = sDegI[2 * t], d1 = sDegI[2 * t + 1];
        int v = d0 + d1;
#pragma unroll
        for (int off = 1; off < 64; off <<= 1) {
            int u = __shfl_up(v, off);
            if (t >= off) v += u;
        }
        int excl = v - d0 - d1;
        sRow[2 * t] = excl;       sRow[2 * t + 1] = excl + d0;
        sCur[2 * t] = excl;       sCur[2 * t + 1] = excl + d0;
    } else if (t < 192) {
        sScore[t - 64] = 0.f;
    }
    __syncthreads();                                   // B2

    // ---- P3: payload CSR placement ----
    {
        int pos = atomicAdd(&sCur[ed], 1);
        sP[pos] = make_uint2(__float_as_uint(ev), (unsigned)es);
    }
    __syncthreads();                                   // B3

    // ---- P4: NNConv1 gather -> h1 (sC); fused hwnN1 ----
#pragma unroll
    for (int j = 0; j < 4; ++j) {
        int n = (t >> 5) + j * 32;
        int row = sRow[n], cnt = sDegI[n];
        float acc = c1b;
        uint2 pl[8];
#pragma unroll
        for (int jj = 0; jj < 8; ++jj) pl[jj] = sP[row + jj];
#pragma unroll
        for (int jj = 0; jj < 8; ++jj) {
            int s = pl[jj].y & 127;
            float tv = fmaxf(__uint_as_float(pl[jj].x) * w1a + b1a, 0.f);
            float contrib = tv * sA[s * H + o5] + sB[s * H + o5];
            acc += (jj < cnt) ? contrib : 0.f;
        }
        for (int jj = 8; jj < cnt; ++jj) {
            uint2 p = sP[row + jj];
            int s = p.y & 127;
            float tv = fmaxf(__uint_as_float(p.x) * w1a + b1a, 0.f);
            acc += tv * sA[s * H + o5] + sB[s * H + o5];
        }
        sC[n * H + o5] = acc;
        float v = acc * p1wv;
#pragma unroll
        for (int m = 16; m >= 1; m >>= 1) v += __shfl_xor(v, m);
        if (o5 == 0) sHwnN[n] = v * rsqrtf(fmaxf((float)sDegO[n], 1.f));
    }
    __syncthreads();                                   // B4

    // ---- P5: agg1 (one edge/thread) ----
    atomicAdd(&sScore[ed], sHwnN[es]);
    __syncthreads();                                   // B5

    // ---- P6: score1 ----
    if (t < Nn) {
        float v = sScore[t] * rsqrtf(fmaxf((float)sDegI[t], 1.f)) + p1b;
        float sc = 1.f / (1.f + expf(-v));
        sScore[t] = sc;
        out_s1[b * Nn + t] = sc;
    }
    __syncthreads();                                   // B6

    // ---- P7: rank1 || zero deg2 counters ----
    if (t < Nn) {
        float my = sScore[t];
        int rank = 0;
#pragma unroll 4
        for (int j = 0; j < Nn; ++j) {
            float sj = sScore[j];
            rank += (sj > my) || (sj == my && j < t);
        }
        sRel[t] = (rank < K1) ? rank : -1;
        if (rank < K1) { sWloc[rank] = t; sWsc[rank] = my; }
    } else if (t < 2 * Nn) {
        sCur[t - Nn] = 0;
    }
    __syncthreads();                                   // B7

    // ---- P8: gather gated h1p -> sA || deg2 count || zero agg2; prefetch n2 cols ----
    {
        int r0 = t >> 5;
        sA[t]        = sC[sWloc[r0] * H + o5] * sWsc[r0];
        int r1 = 32 + r0;
        sA[t + 1024] = sC[sWloc[r1] * H + o5] * sWsc[r1];
    }
    const int rs_e = sRel[es], rd_e = sRel[ed];
    if (rs_e >= 0 && rd_e >= 0) {
        atomicAdd(&sCur[rs_e], 1);          // outdeg2
        atomicAdd(&sCur[64 + rd_e], 1);     // indeg2
    }
    if (t >= 960) sScore[64 + (t - 960)] = 0.f;        // agg2 accumulator zero
    float w2c2[H], b2c2[H];
#pragma unroll
    for (int k = 0; k < H; ++k) {
        w2c2[k] = n2_w2[k * H + o5];
        b2c2[k] = n2_b2[k * H + o5];
    }
    __syncthreads();                                   // B8

    // ---- P9: NNConv2 matvec (hw2b, hbb) ----
#pragma unroll
    for (int j = 0; j < 2; ++j) {
        int i = t + j * 1024;
        int n = i >> 5;
        const float* hn = &sA[n * H];
        float sw = 0.f, sb = 0.f;
#pragma unroll
        for (int k = 0; k < H; ++k) { float hv = hn[k]; sw += hv * w2c2[k]; sb += hv * b2c2[k]; }
        sB[i] = sw; sB[2048 + i] = sb;
    }
    __syncthreads();                                   // B9

    // ---- P10: NNConv2 gather -> h2 (sC[0:2048]); fused hwnN2 ----
#pragma unroll
    for (int j = 0; j < 2; ++j) {
        int i = t + j * 1024;
        int r = i >> 5;                                // kept idx 0..63
        int n = sWloc[r];
        int row = sRow[n], cnt = sDegI[n];
        float acc = c2b;
        uint2 pl[8];
#pragma unroll
        for (int jj = 0; jj < 8; ++jj) pl[jj] = sP[row + jj];
#pragma unroll
        for (int jj = 0; jj < 8; ++jj) {
            int s = pl[jj].y & 127;
            int rs = sRel[s];
            int rsm = rs < 0 ? 0 : rs;
            float tv = fmaxf(__uint_as_float(pl[jj].x) * w1b + b1b, 0.f);
            float contrib = tv * sB[rsm * H + o5] + sB[2048 + rsm * H + o5];
            acc += (jj < cnt && rs >= 0) ? contrib : 0.f;
        }
        for (int jj = 8; jj < cnt; ++jj) {
            uint2 p = sP[row + jj];
            int s = p.y & 127;
            int rs = sRel[s];
            if (rs >= 0) {
                float tv = fmaxf(__uint_as_float(p.x) * w1b + b1b, 0.f);
                acc += tv * sB[rs * H + o5] + sB[2048 + rs * H + o5];
            }
        }
        sC[r * H + o5] = acc;
        float v = acc * p2wv;
#pragma unroll
        for (int m = 16; m >= 1; m >>= 1) v += __shfl_xor(v, m);
        if (o5 == 0) sHwnN[r] = v * rsqrtf(fmaxf((float)sCur[r], 1.f));
    }
    __syncthreads();                                   // B10

    // ---- P11: agg2 (one edge/thread) || readout g1 ----
    if (rs_e >= 0 && rd_e >= 0) atomicAdd(&sScore[64 + rd_e], sHwnN[rs_e]);
    if (t < 2 * H) {
        if (t < H) {
            float s = 0.f;
#pragma unroll 8
            for (int j = 0; j < K1; ++j) s += sA[j * H + o5];
            sG1[o5] = s * (1.f / K1);
        } else {
            float m = -INFINITY;
#pragma unroll 8
            for (int j = 0; j < K1; ++j) m = fmaxf(m, sA[j * H + o5]);
            sG1[H + o5] = m;
        }
    }
    __syncthreads();                                   // B11

    // ---- P12: score2 ----
    if (t < K1) {
        float v = sScore[64 + t] * rsqrtf(fmaxf((float)sCur[64 + t], 1.f)) + p2b;
        float sc = 1.f / (1.f + expf(-v));
        sScore[t] = sc;
        out_s2[b * K1 + t] = sc;
    }
    __syncthreads();                                   // B12

    // ---- P13: rank2 ----
    if (t < K1) {
        float my = sScore[t];
        int rank = 0;
#pragma unroll 4
        for (int j = 0; j < K1; ++j) {
            float sj = sScore[j];
            rank += (sj > my) || (sj == my && j < t);
        }
        if (rank < K2) { sWloc[rank] = t; sWsc[rank] = my; }
    }
    __syncthreads();                                   // B13

    // ---- P14: fused gather + readout g2; prefetch fc1_w rows ----
    if (t < 2 * H) {
        if (t < H) {
            float s = 0.f;
#pragma unroll 8
            for (int j = 0; j < K2; ++j) s += sC[sWloc[j] * H + o5] * sWsc[j];
            sG2[o5] = s * (1.f / K2);
        } else {
            float m = -INFINITY;
#pragma unroll 8
            for (int j = 0; j < K2; ++j) m = fmaxf(m, sC[sWloc[j] * H + o5] * sWsc[j]);
            sG2[H + o5] = m;
        }
    }
    float f1w[16];
    {
        int o = t & 127, p = t >> 7;
#pragma unroll
        for (int k = 0; k < 16; ++k) f1w[k] = fc1_w[(p * 16 + k) * OUTD + o];
    }
    __syncthreads();                                   // B14

    // ---- P15: fc1 split-k partials (8-way) ----
    {
        int o = t & 127, p = t >> 7;
        float a = 0.f;
#pragma unroll
        for (int k = 0; k < 16; ++k) {
            int kk = p * 16 + k;
            float xv = (kk < 2 * H) ? sG1[kk] : sG2[kk - 2 * H];
            a += xv * f1w[k];
        }
        sB[p * OUTD + o] = a;
    }
    __syncthreads();                                   // B15

    // ---- P16: fc1 reduce + BN+ReLU ----
    if (t < OUTD) {
        float a = fc1_b[t];
#pragma unroll
        for (int p = 0; p < 8; ++p) a += sB[p * OUTD + t];
        sY1[t] = fmaxf(a, 0.f) * inv * bn4_g[t] + bn4_b[t];
    }
    __syncthreads();                                   // B16

    // ---- P17: tail: fc2 + BN + fc3 + log_softmax (wave 0) ----
    if (t < 64) {
        int half = t >> 5;
        float a = 0.f;
#pragma unroll 8
        for (int k = 0; k < 64; ++k) {
            int kk = half * 64 + k;
            a += sY1[kk] * fc2_w[kk * H + o5];
        }
        a += __shfl_xor(a, 32);
        float y2 = fmaxf(a + fc2_b[o5], 0.f) * inv * bn5_g[o5] + bn5_b[o5];
        float v0 = (t < 32) ? y2 * fc3_w[o5 * NC + 0] : 0.f;
        float v1 = (t < 32) ? y2 * fc3_w[o5 * NC + 1] : 0.f;
#pragma unroll
        for (int m = 32; m >= 1; m >>= 1) {
            v0 += __shfl_xor(v0, m);
            v1 += __shfl_xor(v1, m);
        }
        if (t == 0) {
            float z0 = v0 + fc3_b[0], z1 = v1 + fc3_b[1];
            float mm = fmaxf(z0, z1);
            float l = mm + logf(expf(z0 - mm) + expf(z1 - mm));
            out_x[b * NC + 0] = z0 - l;
            out_x[b * NC + 1] = z1 - l;
        }
    }
}

// ---------------------------------------------------------------------------
extern "C" void kernel_launch(void* const* d_in, const int* in_sizes, int n_in,
                              void* d_out, int out_size, void* d_ws, size_t ws_size,
                              hipStream_t stream) {
    const float* h       = (const float*)d_in[0];
    const float* e       = (const float*)d_in[1];
    const int*   src     = (const int*)d_in[2];
    const int*   dst     = (const int*)d_in[3];
    const float* n1_w1   = (const float*)d_in[4];
    const float* n1_b1   = (const float*)d_in[5];
    const float* n1_w2   = (const float*)d_in[6];
    const float* n1_b2   = (const float*)d_in[7];
    const float* conv1_b = (const float*)d_in[8];
    const float* p1_w    = (const float*)d_in[9];
    const float* p1_b    = (const float*)d_in[10];
    const float* n2_w1   = (const float*)d_in[11];
    const float* n2_b1   = (const float*)d_in[12];
    const float* n2_w2   = (const float*)d_in[13];
    const float* n2_b2   = (const float*)d_in[14];
    const float* conv2_b = (const float*)d_in[15];
    const float* p2_w    = (const float*)d_in[16];
    const float* p2_b    = (const float*)d_in[17];
    const float* fc1_w   = (const float*)d_in[18];
    const float* fc1_b   = (const float*)d_in[19];
    const float* bn4_g   = (const float*)d_in[20];
    const float* bn4_b   = (const float*)d_in[21];
    const float* fc2_w   = (const float*)d_in[22];
    const float* fc2_b   = (const float*)d_in[23];
    const float* bn5_g   = (const float*)d_in[24];
    const float* bn5_b   = (const float*)d_in[25];
    const float* fc3_w   = (const float*)d_in[26];
    const float* fc3_b   = (const float*)d_in[27];

    float* out_x  = (float*)d_out;
    float* out_s1 = out_x + Bg * NC;
    float* out_s2 = out_s1 + Bg * Nn;

    k_fused<<<Bg, BS, 0, stream>>>(h, e, src, dst,
                                   n1_w1, n1_b1, n1_w2, n1_b2, conv1_b, p1_w, p1_b,
                                   n2_w1, n2_b1, n2_w2, n2_b2, conv2_b, p2_w, p2_b,
                                   fc1_w, fc1_b, bn4_g, bn4_b, fc2_w, fc2_b,
                                   bn5_g, bn5_b, fc3_w, fc3_b,
                                   out_x, out_s1, out_s2);
}

// Round 6
// 135.125 us; speedup vs baseline: 1.7008x; 1.0057x over previous
//
#include <hip/hip_runtime.h>
#include <math.h>

// ---- problem constants ----
constexpr int Bg   = 128;          // graphs
constexpr int Nn   = 128;          // nodes/graph
constexpr int Epg  = Nn * 8;       // 1024 edges/graph
constexpr int IND  = 16;
constexpr int H    = 32;
constexpr int K1   = 64;
constexpr int K2   = 32;
constexpr int OUTD = 128;
constexpr int NC   = 2;
constexpr int BS   = 1024;         // 16 waves

// One block per graph. Payload-CSR, 8-lane-per-node float4 gathers.
__launch_bounds__(BS)
__global__ void k_fused(const float* __restrict__ h, const float* __restrict__ e,
                        const int* __restrict__ src, const int* __restrict__ dst,
                        const float* __restrict__ n1_w1, const float* __restrict__ n1_b1,
                        const float* __restrict__ n1_w2, const float* __restrict__ n1_b2,
                        const float* __restrict__ conv1_b,
                        const float* __restrict__ p1_w, const float* __restrict__ p1_b,
                        const float* __restrict__ n2_w1, const float* __restrict__ n2_b1,
                        const float* __restrict__ n2_w2, const float* __restrict__ n2_b2,
                        const float* __restrict__ conv2_b,
                        const float* __restrict__ p2_w, const float* __restrict__ p2_b,
                        const float* __restrict__ fc1_w, const float* __restrict__ fc1_b,
                        const float* __restrict__ bn4_g, const float* __restrict__ bn4_b,
                        const float* __restrict__ fc2_w, const float* __restrict__ fc2_b,
                        const float* __restrict__ bn5_g, const float* __restrict__ bn5_b,
                        const float* __restrict__ fc3_w, const float* __restrict__ fc3_b,
                        float* __restrict__ out_x, float* __restrict__ out_s1,
                        float* __restrict__ out_s2) {
    __shared__ __align__(16) float sA[4096];   // hw2a | h1p
    __shared__ __align__(16) float sB[4096];   // hba  | hw2b(0:2048)+hbb(2048:4096) | fc1 partials
    __shared__ __align__(16) float sC[4096];   // h-in(0:2048) -> h1 -> h2(0:2048)
    __shared__ uint2 sP[Epg + 16];             // CSR payload: (e_bits, src)
    __shared__ int   sDegO[Nn], sDegI[Nn], sRow[Nn], sCur[Nn];
    __shared__ float sHwnN[Nn];
    __shared__ __align__(16) float sScore[Nn]; // doubles as agg accumulator
    __shared__ int   sRel[Nn], sWloc[K1];
    __shared__ float sWsc[K1], sG1[2 * H], sG2[2 * H], sY1[OUTD];

    const int b = blockIdx.x, t = threadIdx.x;
    const int o5 = t & 31;
    const int l8 = t & 7;            // lane-in-group for 8-lane-per-node phases

    // ---- P0: issue staging loads, stage, zero counters ----
    const float ev = e[b * Epg + t];
    const int   es = src[b * Epg + t] & (Nn - 1);
    const int   ed = dst[b * Epg + t] & (Nn - 1);
    if (t < 512) ((float4*)sC)[t] = ((const float4*)h)[b * 512 + t];
    float w2c[IND], b2c[IND];
#pragma unroll
    for (int k = 0; k < IND; ++k) {
        w2c[k] = n1_w2[k * H + o5];
        b2c[k] = n1_b2[k * H + o5];
    }
    const float w1a = n1_w1[0], b1a = n1_b1[0];
    const float w1b = n2_w1[0], b1b = n2_b1[0];
    const float p1b = p1_b[0],  p2b = p2_b[0];
    const float4 p1w4 = ((const float4*)p1_w)[l8];
    const float4 p2w4 = ((const float4*)p2_w)[l8];
    const float4 c1b4 = ((const float4*)conv1_b)[l8];
    const float4 c2b4 = ((const float4*)conv2_b)[l8];
    const float inv = rsqrtf(1.f + 1e-5f);
    if (t < Nn) { sDegO[t] = 0; sDegI[t] = 0; }
    __syncthreads();                                   // B0

    // ---- P1: degree count || NNConv1 matvec (hw2a, hba), float4 hn reads ----
    atomicAdd(&sDegO[es], 1);
    atomicAdd(&sDegI[ed], 1);
#pragma unroll
    for (int j = 0; j < 4; ++j) {
        int n = (t >> 5) + j * 32;
        const float4* hn4 = (const float4*)&sC[n * IND];
        float4 q0 = hn4[0], q1 = hn4[1], q2 = hn4[2], q3 = hn4[3];
        float hv[IND] = {q0.x,q0.y,q0.z,q0.w, q1.x,q1.y,q1.z,q1.w,
                         q2.x,q2.y,q2.z,q2.w, q3.x,q3.y,q3.z,q3.w};
        float sw = 0.f, sb = 0.f;
#pragma unroll
        for (int k = 0; k < IND; ++k) { sw += hv[k] * w2c[k]; sb += hv[k] * b2c[k]; }
        sA[n * H + o5] = sw;
        sB[n * H + o5] = sb;
    }
    __syncthreads();                                   // B1

    // ---- P2: prefix scan of indeg (wave 0) || zero agg accumulators ----
    if (t < 64) {
        int d0 = sDegI[2 * t], d1 = sDegI[2 * t + 1];
        int v = d0 + d1;
#pragma unroll
        for (int off = 1; off < 64; off <<= 1) {
            int u = __shfl_up(v, off);
            if (t >= off) v += u;
        }
        int excl = v - d0 - d1;
        sRow[2 * t] = excl;       sRow[2 * t + 1] = excl + d0;
        sCur[2 * t] = excl;       sCur[2 * t + 1] = excl + d0;
    } else if (t < 192) {
        sScore[t - 64] = 0.f;
    }
    __syncthreads();                                   // B2

    // ---- P3: payload CSR placement ----
    {
        int pos = atomicAdd(&sCur[ed], 1);
        sP[pos] = make_uint2(__float_as_uint(ev), (unsigned)es);
    }
    __syncthreads();                                   // B3

    // ---- P4: NNConv1 gather (8 lanes/node, float4); fused hwnN1 ----
    {
        int n = t >> 3;
        int row = sRow[n], cnt = sDegI[n];
        float4 acc = c1b4;
        for (int base = 0; base < cnt; base += 8) {
            uint2 pl[8];
#pragma unroll
            for (int jj = 0; jj < 8; ++jj) pl[jj] = sP[row + base + jj];
#pragma unroll
            for (int jj = 0; jj < 8; ++jj) {
                int s = pl[jj].y & 127;
                float tv = fmaxf(__uint_as_float(pl[jj].x) * w1a + b1a, 0.f);
                float4 a4 = *(const float4*)&sA[s * H + l8 * 4];
                float4 b4 = *(const float4*)&sB[s * H + l8 * 4];
                bool on = (base + jj) < cnt;
                acc.x += on ? (tv * a4.x + b4.x) : 0.f;
                acc.y += on ? (tv * a4.y + b4.y) : 0.f;
                acc.z += on ? (tv * a4.z + b4.z) : 0.f;
                acc.w += on ? (tv * a4.w + b4.w) : 0.f;
            }
        }
        *(float4*)&sC[n * H + l8 * 4] = acc;
        float v = acc.x * p1w4.x + acc.y * p1w4.y + acc.z * p1w4.z + acc.w * p1w4.w;
        v += __shfl_xor(v, 1); v += __shfl_xor(v, 2); v += __shfl_xor(v, 4);
        if (l8 == 0) sHwnN[n] = v * rsqrtf(fmaxf((float)sDegO[n], 1.f));
    }
    __syncthreads();                                   // B4

    // ---- P5: agg1 (one edge/thread) ----
    atomicAdd(&sScore[ed], sHwnN[es]);
    __syncthreads();                                   // B5

    // ---- P6: score1 || zero deg2 counters ----
    if (t < Nn) {
        float v = sScore[t] * rsqrtf(fmaxf((float)sDegI[t], 1.f)) + p1b;
        float sc = 1.f / (1.f + expf(-v));
        sScore[t] = sc;
        out_s1[b * Nn + t] = sc;
    } else if (t < 2 * Nn) {
        sCur[t - Nn] = 0;
    }
    __syncthreads();                                   // B6

    // ---- P7: rank1 (float4 reads) ----
    if (t < Nn) {
        float my = sScore[t];
        int rank = 0;
#pragma unroll 8
        for (int j4 = 0; j4 < Nn / 4; ++j4) {
            float4 s4 = ((const float4*)sScore)[j4];
            int j = j4 * 4;
            rank += (s4.x > my) || (s4.x == my && j + 0 < t);
            rank += (s4.y > my) || (s4.y == my && j + 1 < t);
            rank += (s4.z > my) || (s4.z == my && j + 2 < t);
            rank += (s4.w > my) || (s4.w == my && j + 3 < t);
        }
        sRel[t] = (rank < K1) ? rank : -1;
        if (rank < K1) { sWloc[rank] = t; sWsc[rank] = my; }
    }
    __syncthreads();                                   // B7

    // ---- P8: gather gated h1p -> sA (float4) || deg2 count || zero agg2 ----
    const int rs_e = sRel[es], rd_e = sRel[ed];
    if (t < 512) {
        int r = t >> 3;
        float4 v4 = *(const float4*)&sC[sWloc[r] * H + l8 * 4];
        float sc = sWsc[r];
        v4.x *= sc; v4.y *= sc; v4.z *= sc; v4.w *= sc;
        *(float4*)&sA[r * H + l8 * 4] = v4;
    } else if (t < 576) {
        sScore[64 + (t - 512)] = 0.f;                  // agg2 accumulator zero
    }
    if (rs_e >= 0 && rd_e >= 0) {
        atomicAdd(&sCur[rs_e], 1);          // outdeg2
        atomicAdd(&sCur[64 + rd_e], 1);     // indeg2
    }
    __syncthreads();                                   // B8

    // ---- P9: NNConv2 matvec (hw2b, hbb), float4 hn reads ----
#pragma unroll
    for (int j = 0; j < 2; ++j) {
        int i = t + j * 1024;
        int n = i >> 5;
        const float4* hn4 = (const float4*)&sA[n * H];
        float hv[H];
#pragma unroll
        for (int q = 0; q < 8; ++q) {
            float4 qv = hn4[q];
            hv[q * 4 + 0] = qv.x; hv[q * 4 + 1] = qv.y;
            hv[q * 4 + 2] = qv.z; hv[q * 4 + 3] = qv.w;
        }
        float sw = 0.f, sb = 0.f;
#pragma unroll
        for (int k = 0; k < H; ++k) {
            sw += hv[k] * n2_w2[k * H + o5];
            sb += hv[k] * n2_b2[k * H + o5];
        }
        sB[i] = sw; sB[2048 + i] = sb;
    }
    __syncthreads();                                   // B9

    // ---- P10: NNConv2 gather (8 lanes/kept-node, float4) || readout g1 ----
    if (t < 512) {
        int r = t >> 3;                                // kept idx 0..63
        int n = sWloc[r];
        int row = sRow[n], cnt = sDegI[n];
        float4 acc = c2b4;
        for (int base = 0; base < cnt; base += 8) {
            uint2 pl[8];
#pragma unroll
            for (int jj = 0; jj < 8; ++jj) pl[jj] = sP[row + base + jj];
#pragma unroll
            for (int jj = 0; jj < 8; ++jj) {
                int s = pl[jj].y & 127;
                int rs = sRel[s];
                int rsm = rs < 0 ? 0 : rs;
                float tv = fmaxf(__uint_as_float(pl[jj].x) * w1b + b1b, 0.f);
                float4 a4 = *(const float4*)&sB[rsm * H + l8 * 4];
                float4 b4 = *(const float4*)&sB[2048 + rsm * H + l8 * 4];
                bool on = ((base + jj) < cnt) && (rs >= 0);
                acc.x += on ? (tv * a4.x + b4.x) : 0.f;
                acc.y += on ? (tv * a4.y + b4.y) : 0.f;
                acc.z += on ? (tv * a4.z + b4.z) : 0.f;
                acc.w += on ? (tv * a4.w + b4.w) : 0.f;
            }
        }
        *(float4*)&sC[r * H + l8 * 4] = acc;
        float v = acc.x * p2w4.x + acc.y * p2w4.y + acc.z * p2w4.z + acc.w * p2w4.w;
        v += __shfl_xor(v, 1); v += __shfl_xor(v, 2); v += __shfl_xor(v, 4);
        if (l8 == 0) sHwnN[r] = v * rsqrtf(fmaxf((float)sCur[r], 1.f));
    } else if (t < 576) {
        int t2 = t - 512;
        int o = t2 & 31;
        if (t2 < H) {
            float s = 0.f;
#pragma unroll 8
            for (int j = 0; j < K1; ++j) s += sA[j * H + o];
            sG1[o] = s * (1.f / K1);
        } else {
            float m = -INFINITY;
#pragma unroll 8
            for (int j = 0; j < K1; ++j) m = fmaxf(m, sA[j * H + o]);
            sG1[H + o] = m;
        }
    }
    __syncthreads();                                   // B10

    // ---- P11: agg2 (one edge/thread) ----
    if (rs_e >= 0 && rd_e >= 0) atomicAdd(&sScore[64 + rd_e], sHwnN[rs_e]);
    __syncthreads();                                   // B11

    // ---- P12: score2 ----
    if (t < K1) {
        float v = sScore[64 + t] * rsqrtf(fmaxf((float)sCur[64 + t], 1.f)) + p2b;
        float sc = 1.f / (1.f + expf(-v));
        sScore[t] = sc;
        out_s2[b * K1 + t] = sc;
    }
    __syncthreads();                                   // B12

    // ---- P13: rank2 (float4 reads) ----
    if (t < K1) {
        float my = sScore[t];
        int rank = 0;
#pragma unroll 4
        for (int j4 = 0; j4 < K1 / 4; ++j4) {
            float4 s4 = ((const float4*)sScore)[j4];
            int j = j4 * 4;
            rank += (s4.x > my) || (s4.x == my && j + 0 < t);
            rank += (s4.y > my) || (s4.y == my && j + 1 < t);
            rank += (s4.z > my) || (s4.z == my && j + 2 < t);
            rank += (s4.w > my) || (s4.w == my && j + 3 < t);
        }
        if (rank < K2) { sWloc[rank] = t; sWsc[rank] = my; }
    }
    __syncthreads();                                   // B13

    // ---- P14: fused gather + readout g2 || prefetch fc1_w rows ----
    if (t < 2 * H) {
        int o = t & 31;
        if (t < H) {
            float s = 0.f;
#pragma unroll 8
            for (int j = 0; j < K2; ++j) s += sC[sWloc[j] * H + o] * sWsc[j];
            sG2[o] = s * (1.f / K2);
        } else {
            float m = -INFINITY;
#pragma unroll 8
            for (int j = 0; j < K2; ++j) m = fmaxf(m, sC[sWloc[j] * H + o] * sWsc[j]);
            sG2[H + o] = m;
        }
    }
    float f1w[16];
    {
        int o = t & 127, p = t >> 7;
#pragma unroll
        for (int k = 0; k < 16; ++k) f1w[k] = fc1_w[(p * 16 + k) * OUTD + o];
    }
    __syncthreads();                                   // B14

    // ---- P15: fc1 split-k partials (8-way) ----
    {
        int o = t & 127, p = t >> 7;
        float a = 0.f;
#pragma unroll
        for (int k = 0; k < 16; ++k) {
            int kk = p * 16 + k;
            float xv = (kk < 2 * H) ? sG1[kk] : sG2[kk - 2 * H];
            a += xv * f1w[k];
        }
        sB[p * OUTD + o] = a;
    }
    __syncthreads();                                   // B15

    // ---- P16: fc1 reduce + BN+ReLU ----
    if (t < OUTD) {
        float a = fc1_b[t];
#pragma unroll
        for (int p = 0; p < 8; ++p) a += sB[p * OUTD + t];
        sY1[t] = fmaxf(a, 0.f) * inv * bn4_g[t] + bn4_b[t];
    }
    __syncthreads();                                   // B16

    // ---- P17: tail: fc2 + BN + fc3 + log_softmax (wave 0) ----
    if (t < 64) {
        int half = t >> 5;
        float a = 0.f;
#pragma unroll 8
        for (int k = 0; k < 64; ++k) {
            int kk = half * 64 + k;
            a += sY1[kk] * fc2_w[kk * H + o5];
        }
        a += __shfl_xor(a, 32);
        float y2 = fmaxf(a + fc2_b[o5], 0.f) * inv * bn5_g[o5] + bn5_b[o5];
        float v0 = (t < 32) ? y2 * fc3_w[o5 * NC + 0] : 0.f;
        float v1 = (t < 32) ? y2 * fc3_w[o5 * NC + 1] : 0.f;
#pragma unroll
        for (int m = 32; m >= 1; m >>= 1) {
            v0 += __shfl_xor(v0, m);
            v1 += __shfl_xor(v1, m);
        }
        if (t == 0) {
            float z0 = v0 + fc3_b[0], z1 = v1 + fc3_b[1];
            float mm = fmaxf(z0, z1);
            float l = mm + logf(expf(z0 - mm) + expf(z1 - mm));
            out_x[b * NC + 0] = z0 - l;
            out_x[b * NC + 1] = z1 - l;
        }
    }
}

// ---------------------------------------------------------------------------
extern "C" void kernel_launch(void* const* d_in, const int* in_sizes, int n_in,
                              void* d_out, int out_size, void* d_ws, size_t ws_size,
                              hipStream_t stream) {
    const float* h       = (const float*)d_in[0];
    const float* e       = (const float*)d_in[1];
    const int*   src     = (const int*)d_in[2];
    const int*   dst     = (const int*)d_in[3];
    const float* n1_w1   = (const float*)d_in[4];
    const float* n1_b1   = (const float*)d_in[5];
    const float* n1_w2   = (const float*)d_in[6];
    const float* n1_b2   = (const float*)d_in[7];
    const float* conv1_b = (const float*)d_in[8];
    const float* p1_w    = (const float*)d_in[9];
    const float* p1_b    = (const float*)d_in[10];
    const float* n2_w1   = (const float*)d_in[11];
    const float* n2_b1   = (const float*)d_in[12];
    const float* n2_w2   = (const float*)d_in[13];
    const float* n2_b2   = (const float*)d_in[14];
    const float* conv2_b = (const float*)d_in[15];
    const float* p2_w    = (const float*)d_in[16];
    const float* p2_b    = (const float*)d_in[17];
    const float* fc1_w   = (const float*)d_in[18];
    const float* fc1_b   = (const float*)d_in[19];
    const float* bn4_g   = (const float*)d_in[20];
    const float* bn4_b   = (const float*)d_in[21];
    const float* fc2_w   = (const float*)d_in[22];
    const float* fc2_b   = (const float*)d_in[23];
    const float* bn5_g   = (const float*)d_in[24];
    const float* bn5_b   = (const float*)d_in[25];
    const float* fc3_w   = (const float*)d_in[26];
    const float* fc3_b   = (const float*)d_in[27];

    float* out_x  = (float*)d_out;
    float* out_s1 = out_x + Bg * NC;
    float* out_s2 = out_s1 + Bg * Nn;

    k_fused<<<Bg, BS, 0, stream>>>(h, e, src, dst,
                                   n1_w1, n1_b1, n1_w2, n1_b2, conv1_b, p1_w, p1_b,
                                   n2_w1, n2_b1, n2_w2, n2_b2, conv2_b, p2_w, p2_b,
                                   fc1_w, fc1_b, bn4_g, bn4_b, fc2_w, fc2_b,
                                   bn5_g, bn5_b, fc3_w, fc3_b,
                                   out_x, out_s1, out_s2);
}

// Round 7
// 134.517 us; speedup vs baseline: 1.7085x; 1.0045x over previous
//
#include <hip/hip_runtime.h>
#include <math.h>

// ---- problem constants ----
constexpr int Bg   = 128;          // graphs
constexpr int Nn   = 128;          // nodes/graph
constexpr int Epg  = Nn * 8;       // 1024 edges/graph
constexpr int IND  = 16;
constexpr int H    = 32;
constexpr int K1   = 64;
constexpr int K2   = 32;
constexpr int OUTD = 128;
constexpr int NC   = 2;
constexpr int BS   = 1024;         // 16 waves

// One block per graph. Payload-CSR, gather-everything, 14 barriers.
__launch_bounds__(BS)
__global__ void k_fused(const float* __restrict__ h, const float* __restrict__ e,
                        const int* __restrict__ src, const int* __restrict__ dst,
                        const float* __restrict__ n1_w1, const float* __restrict__ n1_b1,
                        const float* __restrict__ n1_w2, const float* __restrict__ n1_b2,
                        const float* __restrict__ conv1_b,
                        const float* __restrict__ p1_w, const float* __restrict__ p1_b,
                        const float* __restrict__ n2_w1, const float* __restrict__ n2_b1,
                        const float* __restrict__ n2_w2, const float* __restrict__ n2_b2,
                        const float* __restrict__ conv2_b,
                        const float* __restrict__ p2_w, const float* __restrict__ p2_b,
                        const float* __restrict__ fc1_w, const float* __restrict__ fc1_b,
                        const float* __restrict__ bn4_g, const float* __restrict__ bn4_b,
                        const float* __restrict__ fc2_w, const float* __restrict__ fc2_b,
                        const float* __restrict__ bn5_g, const float* __restrict__ bn5_b,
                        const float* __restrict__ fc3_w, const float* __restrict__ fc3_b,
                        float* __restrict__ out_x, float* __restrict__ out_s1,
                        float* __restrict__ out_s2) {
    __shared__ __align__(16) float sA[4096];   // hw2a | h1p
    __shared__ __align__(16) float sB[4096];   // hba  | hw2b(0:2048)+hbb(2048:4096)
    __shared__ __align__(16) float sC[4096];   // h-in -> h1 -> h2(0:2048)
    __shared__ uint2 sP[Epg + 16];             // CSR payload: (e_bits, src)
    __shared__ int   sDegO[Nn], sDegI[Nn], sRow[Nn], sCur[Nn];
    __shared__ float sHwnN[Nn];
    __shared__ __align__(16) float sScore[Nn];
    __shared__ int   sRel[Nn], sWloc[K1];
    __shared__ float sWsc[K1], sG1[2 * H], sG2[2 * H], sY1[OUTD];

    const int b = blockIdx.x, t = threadIdx.x;
    const int o5 = t & 31;
    const int l8 = t & 7;

    // ---- P0: stage inputs; prefetch n1 weight columns; zero degs ----
    const float ev = e[b * Epg + t];
    const int   es = src[b * Epg + t] & (Nn - 1);
    const int   ed = dst[b * Epg + t] & (Nn - 1);
    if (t < 512) ((float4*)sC)[t] = ((const float4*)h)[b * 512 + t];
    float w2c[IND], b2c[IND];
#pragma unroll
    for (int k = 0; k < IND; ++k) {
        w2c[k] = n1_w2[k * H + o5];
        b2c[k] = n1_b2[k * H + o5];
    }
    const float w1a = n1_w1[0], b1a = n1_b1[0];
    const float w1b = n2_w1[0], b1b = n2_b1[0];
    const float p1b = p1_b[0],  p2b = p2_b[0];
    const float4 p1w4 = ((const float4*)p1_w)[l8];
    const float4 p2w4 = ((const float4*)p2_w)[l8];
    const float4 c1b4 = ((const float4*)conv1_b)[l8];
    const float4 c2b4 = ((const float4*)conv2_b)[l8];
    const float inv = rsqrtf(1.f + 1e-5f);
    if (t < Nn) { sDegO[t] = 0; sDegI[t] = 0; }
    __syncthreads();                                   // B0

    // ---- P1: degree count || NNConv1 matvec (hw2a, hba) ----
    atomicAdd(&sDegO[es], 1);
    atomicAdd(&sDegI[ed], 1);
#pragma unroll
    for (int j = 0; j < 4; ++j) {
        int n = (t >> 5) + j * 32;
        const float4* hn4 = (const float4*)&sC[n * IND];
        float sw = 0.f, sb = 0.f;
#pragma unroll
        for (int q = 0; q < 4; ++q) {
            float4 qv = hn4[q];
            sw += qv.x * w2c[q*4+0] + qv.y * w2c[q*4+1] + qv.z * w2c[q*4+2] + qv.w * w2c[q*4+3];
            sb += qv.x * b2c[q*4+0] + qv.y * b2c[q*4+1] + qv.z * b2c[q*4+2] + qv.w * b2c[q*4+3];
        }
        sA[n * H + o5] = sw;
        sB[n * H + o5] = sb;
    }
    __syncthreads();                                   // B1

    // ---- P2: prefix scan of indeg (wave 0) ----
    if (t < 64) {
        int d0 = sDegI[2 * t], d1 = sDegI[2 * t + 1];
        int v = d0 + d1;
#pragma unroll
        for (int off = 1; off < 64; off <<= 1) {
            int u = __shfl_up(v, off);
            if (t >= off) v += u;
        }
        int excl = v - d0 - d1;
        sRow[2 * t] = excl;       sRow[2 * t + 1] = excl + d0;
        sCur[2 * t] = excl;       sCur[2 * t + 1] = excl + d0;
    }
    __syncthreads();                                   // B2

    // ---- P3: payload CSR placement (counting sort by dst) ----
    {
        int pos = atomicAdd(&sCur[ed], 1);
        sP[pos] = make_uint2(__float_as_uint(ev), (unsigned)es);
    }
    __syncthreads();                                   // B3

    // ---- P4: NNConv1 gather (8 lanes/node, float4) + fused normalized hwn ----
    {
        int n = t >> 3;
        int row = sRow[n], cnt = sDegI[n];
        float4 acc = c1b4;
        for (int base = 0; base < cnt; base += 8) {
            uint2 pl[8];
#pragma unroll
            for (int jj = 0; jj < 8; ++jj) pl[jj] = sP[row + base + jj];
#pragma unroll
            for (int jj = 0; jj < 8; ++jj) {
                int s = pl[jj].y & 127;
                float tv = fmaxf(__uint_as_float(pl[jj].x) * w1a + b1a, 0.f);
                float4 a4 = *(const float4*)&sA[s * H + l8 * 4];
                float4 b4 = *(const float4*)&sB[s * H + l8 * 4];
                bool on = (base + jj) < cnt;
                acc.x += on ? (tv * a4.x + b4.x) : 0.f;
                acc.y += on ? (tv * a4.y + b4.y) : 0.f;
                acc.z += on ? (tv * a4.z + b4.z) : 0.f;
                acc.w += on ? (tv * a4.w + b4.w) : 0.f;
            }
        }
        *(float4*)&sC[n * H + l8 * 4] = acc;
        float v = acc.x * p1w4.x + acc.y * p1w4.y + acc.z * p1w4.z + acc.w * p1w4.w;
        v += __shfl_xor(v, 1); v += __shfl_xor(v, 2); v += __shfl_xor(v, 4);
        if (l8 == 0) sHwnN[n] = v * rsqrtf(fmaxf((float)sDegO[n], 1.f));
    }
    __syncthreads();                                   // B4

    // ---- P5: score1 gather (2 lanes/node) || zero deg2 || prefetch n2 cols ----
    if (t < 256) {
        int n = t >> 1, l2 = t & 1;
        int row = sRow[n], cnt = sDegI[n];
        float acc = 0.f;
        for (int jj = l2; jj < cnt; jj += 2) {
            uint2 p = sP[row + jj];
            acc += sHwnN[p.y & 127];
        }
        acc += __shfl_xor(acc, 1);
        if (l2 == 0) {
            float v = acc * rsqrtf(fmaxf((float)sDegI[n], 1.f)) + p1b;
            float sc = 1.f / (1.f + expf(-v));
            sScore[n] = sc;
            out_s1[b * Nn + n] = sc;
        }
    } else if (t < 384) {
        sCur[t - 256] = 0;                 // deg2 counters
    }
    float w2c2[H], b2c2[H];
#pragma unroll
    for (int k = 0; k < H; ++k) {
        w2c2[k] = n2_w2[k * H + o5];
        b2c2[k] = n2_b2[k * H + o5];
    }
    __syncthreads();                                   // B5

    // ---- P6: rank1 (float4 reads, 2 waves) ----
    if (t < Nn) {
        float my = sScore[t];
        int rank = 0;
#pragma unroll 8
        for (int j4 = 0; j4 < Nn / 4; ++j4) {
            float4 s4 = ((const float4*)sScore)[j4];
            int j = j4 * 4;
            rank += (s4.x > my) || (s4.x == my && j + 0 < t);
            rank += (s4.y > my) || (s4.y == my && j + 1 < t);
            rank += (s4.z > my) || (s4.z == my && j + 2 < t);
            rank += (s4.w > my) || (s4.w == my && j + 3 < t);
        }
        sRel[t] = (rank < K1) ? rank : -1;
        if (rank < K1) { sWloc[rank] = t; sWsc[rank] = my; }
    }
    __syncthreads();                                   // B6

    // ---- P7: merged h1p write + NNConv2 matvec (reg weights) + deg2 count ----
    {
        const int rs_e = sRel[es], rd_e = sRel[ed];
        if (rs_e >= 0 && rd_e >= 0) {
            atomicAdd(&sCur[rs_e], 1);          // outdeg2
            atomicAdd(&sCur[64 + rd_e], 1);     // indeg2
        }
    }
#pragma unroll
    for (int j = 0; j < 2; ++j) {
        int r = (t >> 5) + j * 32;             // kept idx 0..63
        int n = sWloc[r];
        float g = sWsc[r];
        const float4* hn4 = (const float4*)&sC[n * H];
        float sw = 0.f, sb = 0.f;
#pragma unroll
        for (int q = 0; q < 8; ++q) {
            float4 qv = hn4[q];
            sw += qv.x * w2c2[q*4+0] + qv.y * w2c2[q*4+1] + qv.z * w2c2[q*4+2] + qv.w * w2c2[q*4+3];
            sb += qv.x * b2c2[q*4+0] + qv.y * b2c2[q*4+1] + qv.z * b2c2[q*4+2] + qv.w * b2c2[q*4+3];
        }
        sA[r * H + o5] = sC[n * H + o5] * g;   // h1p element (for g1 readout)
        sB[r * H + o5] = sw * g;               // hw2b
        sB[2048 + r * H + o5] = sb * g;        // hbb
    }
    __syncthreads();                                   // B7

    // ---- P8: NNConv2 gather (8 lanes/kept, float4) + hwnN2 || readout g1 ----
    if (t < 512) {
        int r = t >> 3;
        int n = sWloc[r];
        int row = sRow[n], cnt = sDegI[n];
        float4 acc = c2b4;
        for (int base = 0; base < cnt; base += 8) {
            uint2 pl[8];
#pragma unroll
            for (int jj = 0; jj < 8; ++jj) pl[jj] = sP[row + base + jj];
#pragma unroll
            for (int jj = 0; jj < 8; ++jj) {
                int s = pl[jj].y & 127;
                int rs = sRel[s];
                int rsm = rs < 0 ? 0 : rs;
                float tv = fmaxf(__uint_as_float(pl[jj].x) * w1b + b1b, 0.f);
                float4 a4 = *(const float4*)&sB[rsm * H + l8 * 4];
                float4 b4 = *(const float4*)&sB[2048 + rsm * H + l8 * 4];
                bool on = ((base + jj) < cnt) && (rs >= 0);
                acc.x += on ? (tv * a4.x + b4.x) : 0.f;
                acc.y += on ? (tv * a4.y + b4.y) : 0.f;
                acc.z += on ? (tv * a4.z + b4.z) : 0.f;
                acc.w += on ? (tv * a4.w + b4.w) : 0.f;
            }
        }
        *(float4*)&sC[r * H + l8 * 4] = acc;
        float v = acc.x * p2w4.x + acc.y * p2w4.y + acc.z * p2w4.z + acc.w * p2w4.w;
        v += __shfl_xor(v, 1); v += __shfl_xor(v, 2); v += __shfl_xor(v, 4);
        if (l8 == 0) sHwnN[r] = v * rsqrtf(fmaxf((float)sCur[r], 1.f));
    } else if (t < 576) {
        int t2 = t - 512;
        int o = t2 & 31;
        if (t2 < H) {
            float s = 0.f;
#pragma unroll 8
            for (int j = 0; j < K1; ++j) s += sA[j * H + o];
            sG1[o] = s * (1.f / K1);
        } else {
            float m = -INFINITY;
#pragma unroll 8
            for (int j = 0; j < K1; ++j) m = fmaxf(m, sA[j * H + o]);
            sG1[H + o] = m;
        }
    }
    __syncthreads();                                   // B8

    // ---- P9: score2 gather (4 lanes/kept node) ----
    if (t < 256) {
        int r = t >> 2, l4 = t & 3;
        int n = sWloc[r];
        int row = sRow[n], cnt = sDegI[n];
        float acc = 0.f;
        for (int jj = l4; jj < cnt; jj += 4) {
            uint2 p = sP[row + jj];
            int rs = sRel[p.y & 127];
            if (rs >= 0) acc += sHwnN[rs];
        }
        acc += __shfl_xor(acc, 1);
        acc += __shfl_xor(acc, 2);
        if (l4 == 0) {
            float v = acc * rsqrtf(fmaxf((float)sCur[64 + r], 1.f)) + p2b;
            float sc = 1.f / (1.f + expf(-v));
            sScore[r] = sc;
            out_s2[b * K1 + r] = sc;
        }
    }
    __syncthreads();                                   // B9

    // ---- P10: rank2 (1 wave) ----
    if (t < K1) {
        float my = sScore[t];
        int rank = 0;
#pragma unroll 4
        for (int j4 = 0; j4 < K1 / 4; ++j4) {
            float4 s4 = ((const float4*)sScore)[j4];
            int j = j4 * 4;
            rank += (s4.x > my) || (s4.x == my && j + 0 < t);
            rank += (s4.y > my) || (s4.y == my && j + 1 < t);
            rank += (s4.z > my) || (s4.z == my && j + 2 < t);
            rank += (s4.w > my) || (s4.w == my && j + 3 < t);
        }
        if (rank < K2) { sWloc[rank] = t; sWsc[rank] = my; }
    }
    __syncthreads();                                   // B10

    // ---- P11: readout g2 || prefetch fc1_w (all threads, 8-lane mapping) ----
    if (t < 2 * H) {
        int o = t & 31;
        if (t < H) {
            float s = 0.f;
#pragma unroll 8
            for (int j = 0; j < K2; ++j) s += sC[sWloc[j] * H + o] * sWsc[j];
            sG2[o] = s * (1.f / K2);
        } else {
            float m = -INFINITY;
#pragma unroll 8
            for (int j = 0; j < K2; ++j) m = fmaxf(m, sC[sWloc[j] * H + o] * sWsc[j]);
            sG2[H + o] = m;
        }
    }
    float f1w[16];
    {
        int o = t >> 3, p = t & 7;
#pragma unroll
        for (int k = 0; k < 16; ++k) f1w[k] = fc1_w[(p * 16 + k) * OUTD + o];
    }
    __syncthreads();                                   // B11

    // ---- P12: fc1 via 8-lane shfl reduce + BN+ReLU ----
    {
        int o = t >> 3, p = t & 7;
        float a = 0.f;
#pragma unroll
        for (int k = 0; k < 16; ++k) {
            int kk = p * 16 + k;
            float xv = (kk < 2 * H) ? sG1[kk] : sG2[kk - 2 * H];
            a += xv * f1w[k];
        }
        a += __shfl_xor(a, 1); a += __shfl_xor(a, 2); a += __shfl_xor(a, 4);
        if (p == 0) {
            float aa = a + fc1_b[o];
            sY1[o] = fmaxf(aa, 0.f) * inv * bn4_g[o] + bn4_b[o];
        }
    }
    __syncthreads();                                   // B12

    // ---- P13: tail: fc2 + BN + fc3 + log_softmax (wave 0) ----
    if (t < 64) {
        int half = t >> 5;
        float a = 0.f;
#pragma unroll 8
        for (int k = 0; k < 64; ++k) {
            int kk = half * 64 + k;
            a += sY1[kk] * fc2_w[kk * H + o5];
        }
        a += __shfl_xor(a, 32);
        float y2 = fmaxf(a + fc2_b[o5], 0.f) * inv * bn5_g[o5] + bn5_b[o5];
        float v0 = (t < 32) ? y2 * fc3_w[o5 * NC + 0] : 0.f;
        float v1 = (t < 32) ? y2 * fc3_w[o5 * NC + 1] : 0.f;
#pragma unroll
        for (int m = 32; m >= 1; m >>= 1) {
            v0 += __shfl_xor(v0, m);
            v1 += __shfl_xor(v1, m);
        }
        if (t == 0) {
            float z0 = v0 + fc3_b[0], z1 = v1 + fc3_b[1];
            float mm = fmaxf(z0, z1);
            float l = mm + logf(expf(z0 - mm) + expf(z1 - mm));
            out_x[b * NC + 0] = z0 - l;
            out_x[b * NC + 1] = z1 - l;
        }
    }
}

// ---------------------------------------------------------------------------
extern "C" void kernel_launch(void* const* d_in, const int* in_sizes, int n_in,
                              void* d_out, int out_size, void* d_ws, size_t ws_size,
                              hipStream_t stream) {
    const float* h       = (const float*)d_in[0];
    const float* e       = (const float*)d_in[1];
    const int*   src     = (const int*)d_in[2];
    const int*   dst     = (const int*)d_in[3];
    const float* n1_w1   = (const float*)d_in[4];
    const float* n1_b1   = (const float*)d_in[5];
    const float* n1_w2   = (const float*)d_in[6];
    const float* n1_b2   = (const float*)d_in[7];
    const float* conv1_b = (const float*)d_in[8];
    const float* p1_w    = (const float*)d_in[9];
    const float* p1_b    = (const float*)d_in[10];
    const float* n2_w1   = (const float*)d_in[11];
    const float* n2_b1   = (const float*)d_in[12];
    const float* n2_w2   = (const float*)d_in[13];
    const float* n2_b2   = (const float*)d_in[14];
    const float* conv2_b = (const float*)d_in[15];
    const float* p2_w    = (const float*)d_in[16];
    const float* p2_b    = (const float*)d_in[17];
    const float* fc1_w   = (const float*)d_in[18];
    const float* fc1_b   = (const float*)d_in[19];
    const float* bn4_g   = (const float*)d_in[20];
    const float* bn4_b   = (const float*)d_in[21];
    const float* fc2_w   = (const float*)d_in[22];
    const float* fc2_b   = (const float*)d_in[23];
    const float* bn5_g   = (const float*)d_in[24];
    const float* bn5_b   = (const float*)d_in[25];
    const float* fc3_w   = (const float*)d_in[26];
    const float* fc3_b   = (const float*)d_in[27];

    float* out_x  = (float*)d_out;
    float* out_s1 = out_x + Bg * NC;
    float* out_s2 = out_s1 + Bg * Nn;

    k_fused<<<Bg, BS, 0, stream>>>(h, e, src, dst,
                                   n1_w1, n1_b1, n1_w2, n1_b2, conv1_b, p1_w, p1_b,
                                   n2_w1, n2_b1, n2_w2, n2_b2, conv2_b, p2_w, p2_b,
                                   fc1_w, fc1_b, bn4_g, bn4_b, fc2_w, fc2_b,
                                   bn5_g, bn5_b, fc3_w, fc3_b,
                                   out_x, out_s1, out_s2);
}

// Round 8
// 131.207 us; speedup vs baseline: 1.7516x; 1.0252x over previous
//
#include <hip/hip_runtime.h>
#include <math.h>

// ---- problem constants ----
constexpr int Bg   = 128;          // graphs
constexpr int Nn   = 128;          // nodes/graph
constexpr int Epg  = Nn * 8;       // 1024 edges/graph
constexpr int IND  = 16;
constexpr int H    = 32;
constexpr int K1   = 64;
constexpr int K2   = 32;
constexpr int OUTD = 128;
constexpr int NC   = 2;
constexpr int BS   = 1024;         // 16 waves

// One block per graph. Payload-CSR, gather-everything, compact code.
__launch_bounds__(BS)
__global__ void k_fused(const float* __restrict__ h, const float* __restrict__ e,
                        const int* __restrict__ src, const int* __restrict__ dst,
                        const float* __restrict__ n1_w1, const float* __restrict__ n1_b1,
                        const float* __restrict__ n1_w2, const float* __restrict__ n1_b2,
                        const float* __restrict__ conv1_b,
                        const float* __restrict__ p1_w, const float* __restrict__ p1_b,
                        const float* __restrict__ n2_w1, const float* __restrict__ n2_b1,
                        const float* __restrict__ n2_w2, const float* __restrict__ n2_b2,
                        const float* __restrict__ conv2_b,
                        const float* __restrict__ p2_w, const float* __restrict__ p2_b,
                        const float* __restrict__ fc1_w, const float* __restrict__ fc1_b,
                        const float* __restrict__ bn4_g, const float* __restrict__ bn4_b,
                        const float* __restrict__ fc2_w, const float* __restrict__ fc2_b,
                        const float* __restrict__ bn5_g, const float* __restrict__ bn5_b,
                        const float* __restrict__ fc3_w, const float* __restrict__ fc3_b,
                        float* __restrict__ out_x, float* __restrict__ out_s1,
                        float* __restrict__ out_s2) {
    __shared__ __align__(16) float sA[4096];   // hw2a | h1p
    __shared__ __align__(16) float sB[4096];   // hba  | hw2b(0:2048)+hbb(2048:4096)
    __shared__ __align__(16) float sC[4096];   // h-in -> h1 -> h2(0:2048)
    __shared__ uint2 sP[Epg + 16];             // CSR payload: (e_bits, src)
    __shared__ int   sDegO[Nn], sDegI[Nn], sRow[Nn], sCur[Nn];
    __shared__ float sHwnN[Nn];
    __shared__ __align__(16) float sScore[Nn];
    __shared__ int   sRel[Nn], sWloc[K1];
    __shared__ float sWsc[K1], sG1[2 * H], sG2[2 * H], sY1[OUTD];

    const int b = blockIdx.x, t = threadIdx.x;
    const int o5 = t & 31;
    const int l8 = t & 7;

    // ---- P0: stage inputs; prefetch n1 weight columns; zero degs ----
    const float ev = e[b * Epg + t];
    const int   es = src[b * Epg + t] & (Nn - 1);
    const int   ed = dst[b * Epg + t] & (Nn - 1);
    if (t < 512) ((float4*)sC)[t] = ((const float4*)h)[b * 512 + t];
    float w2c[IND], b2c[IND];
#pragma unroll
    for (int k = 0; k < IND; ++k) {
        w2c[k] = n1_w2[k * H + o5];
        b2c[k] = n1_b2[k * H + o5];
    }
    const float w1a = n1_w1[0], b1a = n1_b1[0];
    const float w1b = n2_w1[0], b1b = n2_b1[0];
    const float p1b = p1_b[0],  p2b = p2_b[0];
    const float4 p1w4 = ((const float4*)p1_w)[l8];
    const float4 p2w4 = ((const float4*)p2_w)[l8];
    const float4 c1b4 = ((const float4*)conv1_b)[l8];
    const float4 c2b4 = ((const float4*)conv2_b)[l8];
    const float inv = rsqrtf(1.f + 1e-5f);
    if (t < Nn) { sDegO[t] = 0; sDegI[t] = 0; }
    __syncthreads();                                   // B0

    // ---- P1: degree count || NNConv1 matvec (hw2a, hba) ----
    atomicAdd(&sDegO[es], 1);
    atomicAdd(&sDegI[ed], 1);
    for (int j = 0; j < 4; ++j) {
        int n = (t >> 5) + j * 32;
        const float4* hn4 = (const float4*)&sC[n * IND];
        float sw = 0.f, sb = 0.f;
#pragma unroll
        for (int q = 0; q < 4; ++q) {
            float4 qv = hn4[q];
            sw += qv.x * w2c[q*4+0] + qv.y * w2c[q*4+1] + qv.z * w2c[q*4+2] + qv.w * w2c[q*4+3];
            sb += qv.x * b2c[q*4+0] + qv.y * b2c[q*4+1] + qv.z * b2c[q*4+2] + qv.w * b2c[q*4+3];
        }
        sA[n * H + o5] = sw;
        sB[n * H + o5] = sb;
    }
    __syncthreads();                                   // B1

    // ---- P2: prefix scan of indeg (wave 0) ----
    if (t < 64) {
        int d0 = sDegI[2 * t], d1 = sDegI[2 * t + 1];
        int v = d0 + d1;
#pragma unroll
        for (int off = 1; off < 64; off <<= 1) {
            int u = __shfl_up(v, off);
            if (t >= off) v += u;
        }
        int excl = v - d0 - d1;
        sRow[2 * t] = excl;       sRow[2 * t + 1] = excl + d0;
        sCur[2 * t] = excl;       sCur[2 * t + 1] = excl + d0;
    }
    __syncthreads();                                   // B2

    // ---- P3: payload CSR placement (counting sort by dst) ----
    {
        int pos = atomicAdd(&sCur[ed], 1);
        sP[pos] = make_uint2(__float_as_uint(ev), (unsigned)es);
    }
    __syncthreads();                                   // B3

    // ---- P4: NNConv1 gather (8 lanes/node, float4) + fused normalized hwn ----
    {
        int n = t >> 3;
        int row = sRow[n], cnt = sDegI[n];
        float4 acc = c1b4;
        for (int base = 0; base < cnt; base += 8) {
            uint2 pl[8];
#pragma unroll
            for (int jj = 0; jj < 8; ++jj) pl[jj] = sP[row + base + jj];
#pragma unroll
            for (int jj = 0; jj < 8; ++jj) {
                int s = pl[jj].y & 127;
                float tv = fmaxf(__uint_as_float(pl[jj].x) * w1a + b1a, 0.f);
                float4 a4 = *(const float4*)&sA[s * H + l8 * 4];
                float4 b4 = *(const float4*)&sB[s * H + l8 * 4];
                bool on = (base + jj) < cnt;
                acc.x += on ? (tv * a4.x + b4.x) : 0.f;
                acc.y += on ? (tv * a4.y + b4.y) : 0.f;
                acc.z += on ? (tv * a4.z + b4.z) : 0.f;
                acc.w += on ? (tv * a4.w + b4.w) : 0.f;
            }
        }
        *(float4*)&sC[n * H + l8 * 4] = acc;
        float v = acc.x * p1w4.x + acc.y * p1w4.y + acc.z * p1w4.z + acc.w * p1w4.w;
        v += __shfl_xor(v, 1); v += __shfl_xor(v, 2); v += __shfl_xor(v, 4);
        if (l8 == 0) sHwnN[n] = v * rsqrtf(fmaxf((float)sDegO[n], 1.f));
    }
    __syncthreads();                                   // B4

    // ---- P5: score1 gather (2 lanes/node) || zero deg2 counters ----
    if (t < 256) {
        int n = t >> 1, l2 = t & 1;
        int row = sRow[n], cnt = sDegI[n];
        float acc = 0.f;
        for (int jj = l2; jj < cnt; jj += 2) {
            uint2 p = sP[row + jj];
            acc += sHwnN[p.y & 127];
        }
        acc += __shfl_xor(acc, 1);
        if (l2 == 0) {
            float v = acc * rsqrtf(fmaxf((float)sDegI[n], 1.f)) + p1b;
            float sc = 1.f / (1.f + expf(-v));
            sScore[n] = sc;
            out_s1[b * Nn + n] = sc;
        }
    } else if (t < 384) {
        sCur[t - 256] = 0;                 // deg2 counters
    }
    __syncthreads();                                   // B5

    // ---- P6: rank1 (float4 reads, 2 waves) ----
    if (t < Nn) {
        float my = sScore[t];
        int rank = 0;
        for (int j4 = 0; j4 < Nn / 4; ++j4) {
            float4 s4 = ((const float4*)sScore)[j4];
            int j = j4 * 4;
            rank += (s4.x > my) || (s4.x == my && j + 0 < t);
            rank += (s4.y > my) || (s4.y == my && j + 1 < t);
            rank += (s4.z > my) || (s4.z == my && j + 2 < t);
            rank += (s4.w > my) || (s4.w == my && j + 3 < t);
        }
        sRel[t] = (rank < K1) ? rank : -1;
        if (rank < K1) { sWloc[rank] = t; sWsc[rank] = my; }
    }
    __syncthreads();                                   // B6

    // ---- P7: merged h1p write + NNConv2 matvec (weights from L2) + deg2 count ----
    {
        const int rs_e = sRel[es], rd_e = sRel[ed];
        if (rs_e >= 0 && rd_e >= 0) {
            atomicAdd(&sCur[rs_e], 1);          // outdeg2
            atomicAdd(&sCur[64 + rd_e], 1);     // indeg2
        }
    }
    for (int j = 0; j < 2; ++j) {
        int r = (t >> 5) + j * 32;             // kept idx 0..63
        int n = sWloc[r];
        float g = sWsc[r];
        const float4* hn4 = (const float4*)&sC[n * H];
        float sw = 0.f, sb = 0.f;
        for (int q = 0; q < 8; ++q) {
            float4 qv = hn4[q];
            int k = q * 4;
            sw += qv.x * n2_w2[(k+0) * H + o5] + qv.y * n2_w2[(k+1) * H + o5]
                + qv.z * n2_w2[(k+2) * H + o5] + qv.w * n2_w2[(k+3) * H + o5];
            sb += qv.x * n2_b2[(k+0) * H + o5] + qv.y * n2_b2[(k+1) * H + o5]
                + qv.z * n2_b2[(k+2) * H + o5] + qv.w * n2_b2[(k+3) * H + o5];
        }
        sA[r * H + o5] = sC[n * H + o5] * g;   // h1p element (for g1 readout)
        sB[r * H + o5] = sw * g;               // hw2b
        sB[2048 + r * H + o5] = sb * g;        // hbb
    }
    __syncthreads();                                   // B7

    // ---- P8: NNConv2 gather (8 lanes/kept, float4) + hwnN2 || readout g1 ----
    if (t < 512) {
        int r = t >> 3;
        int n = sWloc[r];
        int row = sRow[n], cnt = sDegI[n];
        float4 acc = c2b4;
        for (int base = 0; base < cnt; base += 8) {
            uint2 pl[8];
#pragma unroll
            for (int jj = 0; jj < 8; ++jj) pl[jj] = sP[row + base + jj];
#pragma unroll
            for (int jj = 0; jj < 8; ++jj) {
                int s = pl[jj].y & 127;
                int rs = sRel[s];
                int rsm = rs < 0 ? 0 : rs;
                float tv = fmaxf(__uint_as_float(pl[jj].x) * w1b + b1b, 0.f);
                float4 a4 = *(const float4*)&sB[rsm * H + l8 * 4];
                float4 b4 = *(const float4*)&sB[2048 + rsm * H + l8 * 4];
                bool on = ((base + jj) < cnt) && (rs >= 0);
                acc.x += on ? (tv * a4.x + b4.x) : 0.f;
                acc.y += on ? (tv * a4.y + b4.y) : 0.f;
                acc.z += on ? (tv * a4.z + b4.z) : 0.f;
                acc.w += on ? (tv * a4.w + b4.w) : 0.f;
            }
        }
        *(float4*)&sC[r * H + l8 * 4] = acc;
        float v = acc.x * p2w4.x + acc.y * p2w4.y + acc.z * p2w4.z + acc.w * p2w4.w;
        v += __shfl_xor(v, 1); v += __shfl_xor(v, 2); v += __shfl_xor(v, 4);
        if (l8 == 0) sHwnN[r] = v * rsqrtf(fmaxf((float)sCur[r], 1.f));
    } else if (t < 576) {
        int t2 = t - 512;
        int o = t2 & 31;
        if (t2 < H) {
            float s = 0.f;
            for (int j = 0; j < K1; ++j) s += sA[j * H + o];
            sG1[o] = s * (1.f / K1);
        } else {
            float m = -INFINITY;
            for (int j = 0; j < K1; ++j) m = fmaxf(m, sA[j * H + o]);
            sG1[H + o] = m;
        }
    }
    __syncthreads();                                   // B8

    // ---- P9: score2 gather (4 lanes/kept node) ----
    if (t < 256) {
        int r = t >> 2, l4 = t & 3;
        int n = sWloc[r];
        int row = sRow[n], cnt = sDegI[n];
        float acc = 0.f;
        for (int jj = l4; jj < cnt; jj += 4) {
            uint2 p = sP[row + jj];
            int rs = sRel[p.y & 127];
            if (rs >= 0) acc += sHwnN[rs];
        }
        acc += __shfl_xor(acc, 1);
        acc += __shfl_xor(acc, 2);
        if (l4 == 0) {
            float v = acc * rsqrtf(fmaxf((float)sCur[64 + r], 1.f)) + p2b;
            float sc = 1.f / (1.f + expf(-v));
            sScore[r] = sc;
            out_s2[b * K1 + r] = sc;
        }
    }
    __syncthreads();                                   // B9

    // ---- P10: rank2 (1 wave) ----
    if (t < K1) {
        float my = sScore[t];
        int rank = 0;
        for (int j4 = 0; j4 < K1 / 4; ++j4) {
            float4 s4 = ((const float4*)sScore)[j4];
            int j = j4 * 4;
            rank += (s4.x > my) || (s4.x == my && j + 0 < t);
            rank += (s4.y > my) || (s4.y == my && j + 1 < t);
            rank += (s4.z > my) || (s4.z == my && j + 2 < t);
            rank += (s4.w > my) || (s4.w == my && j + 3 < t);
        }
        if (rank < K2) { sWloc[rank] = t; sWsc[rank] = my; }
    }
    __syncthreads();                                   // B10

    // ---- P11: readout g2 || prefetch fc1_w (8-lane mapping) ----
    if (t < 2 * H) {
        int o = t & 31;
        if (t < H) {
            float s = 0.f;
            for (int j = 0; j < K2; ++j) s += sC[sWloc[j] * H + o] * sWsc[j];
            sG2[o] = s * (1.f / K2);
        } else {
            float m = -INFINITY;
            for (int j = 0; j < K2; ++j) m = fmaxf(m, sC[sWloc[j] * H + o] * sWsc[j]);
            sG2[H + o] = m;
        }
    }
    float f1w[16];
    {
        int o = t >> 3, p = t & 7;
#pragma unroll
        for (int k = 0; k < 16; ++k) f1w[k] = fc1_w[(p * 16 + k) * OUTD + o];
    }
    __syncthreads();                                   // B11

    // ---- P12: fc1 via 8-lane shfl reduce + BN+ReLU ----
    {
        int o = t >> 3, p = t & 7;
        float a = 0.f;
#pragma unroll
        for (int k = 0; k < 16; ++k) {
            int kk = p * 16 + k;
            float xv = (kk < 2 * H) ? sG1[kk] : sG2[kk - 2 * H];
            a += xv * f1w[k];
        }
        a += __shfl_xor(a, 1); a += __shfl_xor(a, 2); a += __shfl_xor(a, 4);
        if (p == 0) {
            float aa = a + fc1_b[o];
            sY1[o] = fmaxf(aa, 0.f) * inv * bn4_g[o] + bn4_b[o];
        }
    }
    __syncthreads();                                   // B12

    // ---- P13: tail: fc2 + BN + fc3 + log_softmax (wave 0) ----
    if (t < 64) {
        int half = t >> 5;
        float a = 0.f;
        for (int k = 0; k < 64; ++k) {
            int kk = half * 64 + k;
            a += sY1[kk] * fc2_w[kk * H + o5];
        }
        a += __shfl_xor(a, 32);
        float y2 = fmaxf(a + fc2_b[o5], 0.f) * inv * bn5_g[o5] + bn5_b[o5];
        float v0 = (t < 32) ? y2 * fc3_w[o5 * NC + 0] : 0.f;
        float v1 = (t < 32) ? y2 * fc3_w[o5 * NC + 1] : 0.f;
#pragma unroll
        for (int m = 32; m >= 1; m >>= 1) {
            v0 += __shfl_xor(v0, m);
            v1 += __shfl_xor(v1, m);
        }
        if (t == 0) {
            float z0 = v0 + fc3_b[0], z1 = v1 + fc3_b[1];
            float mm = fmaxf(z0, z1);
            float l = mm + logf(expf(z0 - mm) + expf(z1 - mm));
            out_x[b * NC + 0] = z0 - l;
            out_x[b * NC + 1] = z1 - l;
        }
    }
}

// ---------------------------------------------------------------------------
extern "C" void kernel_launch(void* const* d_in, const int* in_sizes, int n_in,
                              void* d_out, int out_size, void* d_ws, size_t ws_size,
                              hipStream_t stream) {
    const float* h       = (const float*)d_in[0];
    const float* e       = (const float*)d_in[1];
    const int*   src     = (const int*)d_in[2];
    const int*   dst     = (const int*)d_in[3];
    const float* n1_w1   = (const float*)d_in[4];
    const float* n1_b1   = (const float*)d_in[5];
    const float* n1_w2   = (const float*)d_in[6];
    const float* n1_b2   = (const float*)d_in[7];
    const float* conv1_b = (const float*)d_in[8];
    const float* p1_w    = (const float*)d_in[9];
    const float* p1_b    = (const float*)d_in[10];
    const float* n2_w1   = (const float*)d_in[11];
    const float* n2_b1   = (const float*)d_in[12];
    const float* n2_w2   = (const float*)d_in[13];
    const float* n2_b2   = (const float*)d_in[14];
    const float* conv2_b = (const float*)d_in[15];
    const float* p2_w    = (const float*)d_in[16];
    const float* p2_b    = (const float*)d_in[17];
    const float* fc1_w   = (const float*)d_in[18];
    const float* fc1_b   = (const float*)d_in[19];
    const float* bn4_g   = (const float*)d_in[20];
    const float* bn4_b   = (const float*)d_in[21];
    const float* fc2_w   = (const float*)d_in[22];
    const float* fc2_b   = (const float*)d_in[23];
    const float* bn5_g   = (const float*)d_in[24];
    const float* bn5_b   = (const float*)d_in[25];
    const float* fc3_w   = (const float*)d_in[26];
    const float* fc3_b   = (const float*)d_in[27];

    float* out_x  = (float*)d_out;
    float* out_s1 = out_x + Bg * NC;
    float* out_s2 = out_s1 + Bg * Nn;

    k_fused<<<Bg, BS, 0, stream>>>(h, e, src, dst,
                                   n1_w1, n1_b1, n1_w2, n1_b2, conv1_b, p1_w, p1_b,
                                   n2_w1, n2_b1, n2_w2, n2_b2, conv2_b, p2_w, p2_b,
                                   fc1_w, fc1_b, bn4_g, bn4_b, fc2_w, fc2_b,
                                   bn5_g, bn5_b, fc3_w, fc3_b,
                                   out_x, out_s1, out_s2);
}